// Round 6
// baseline (442.447 us; speedup 1.0000x reference)
//
#include <hip/hip_runtime.h>

typedef __attribute__((ext_vector_type(8))) short short8;
typedef __attribute__((ext_vector_type(4))) float f32x4;

#define EMB 768
#define SEQ 4096
#define NH 12
#define HD 64
// 8 * log2(e): folds the score scale AND the exp->exp2 conversion into Q
#define QSCALE 11.541560327111707f

#define GLOBAL_AS __attribute__((address_space(1)))
#define LDS_AS __attribute__((address_space(3)))

__device__ inline ushort f2bf(float v) {
  union { float f; unsigned int u; } x; x.f = v;
  unsigned int r = x.u + 0x7fffu + ((x.u >> 16) & 1u);
  return (ushort)(r >> 16);
}
__device__ inline float bf2f(ushort u) {
  union { float f; unsigned int u32; } x; x.u32 = ((unsigned int)u) << 16;
  return x.f;
}

__global__ void split_k(const float* __restrict__ src, ushort* __restrict__ hi,
                        ushort* __restrict__ lo, int n) {
  int i = blockIdx.x * blockDim.x + threadIdx.x;
  if (i < n) {
    float v = src[i];
    ushort h = f2bf(v);
    hi[i] = h;
    lo[i] = f2bf(v - bf2f(h));
  }
}

// C[m,n] = sum_k A[m,k]*B[n,k] (both K-contiguous), fp32-accurate via 3-term
// bf16 split MFMA, global_load_lds staging. mode 0: C += bias -> Cout fp32.
// mode 1: scatter QKV; V via LDS transpose -> coalesced swizzled stores.
// Vt swizzle is per-64-key window (chunk ^ dim&7) to match attn's 64-key
// double-buffered DMA tiles.
__global__ __launch_bounds__(256) void gemm_bt_split(
    const ushort* __restrict__ Ah, const ushort* __restrict__ Al,
    const ushort* __restrict__ Bh, const ushort* __restrict__ Bl,
    int M, int N, int K, int mode,
    float* __restrict__ Cout, const float* __restrict__ bias,
    ushort* __restrict__ Qh, ushort* __restrict__ Ql,
    ushort* __restrict__ Kh, ushort* __restrict__ Kl,
    ushort* __restrict__ Vt) {
  __shared__ ushort smem[4 * 128 * 32];
  ushort* sAh = smem;
  ushort* sAl = smem + 4096;
  ushort* sBh = smem + 8192;
  ushort* sBl = smem + 12288;

  const int tid = threadIdx.x;
  const int lane = tid & 63;
  const int w = tid >> 6;
  const int wm = w >> 1, wn = w & 1;
  const int col = lane & 15, quad = lane >> 4;
  const int bm = blockIdx.x, bn = blockIdx.y;

  const ushort* gsrc = (w == 0)   ? Ah + (size_t)bm * 128 * K
                       : (w == 1) ? Al + (size_t)bm * 128 * K
                       : (w == 2) ? Bh + (size_t)bn * 128 * K
                                  : Bl + (size_t)bn * 128 * K;
  ushort* lbase = (w == 0) ? sAh : (w == 1) ? sAl : (w == 2) ? sBh : sBl;
  const ushort* g0 = gsrc + (size_t)(lane >> 2) * K + (lane & 3) * 8;

  f32x4 acc[4][4];
  const f32x4 zz = {0.f, 0.f, 0.f, 0.f};
#pragma unroll
  for (int i = 0; i < 4; ++i)
#pragma unroll
    for (int j = 0; j < 4; ++j) acc[i][j] = zz;

  for (int kt = 0; kt < K; kt += 32) {
    __syncthreads();
#pragma unroll
    for (int i = 0; i < 8; ++i) {
      __builtin_amdgcn_global_load_lds(
          (const GLOBAL_AS unsigned int*)(g0 + (size_t)i * 16 * K + kt),
          (LDS_AS unsigned int*)(lbase + i * 512), 16, 0, 0);
    }
    asm volatile("s_waitcnt vmcnt(0)" ::: "memory");
    __syncthreads();

    short8 fah[4], fal[4], fbh[4], fbl[4];
#pragma unroll
    for (int t = 0; t < 4; ++t) {
      int ra = (wm * 64 + t * 16 + col) * 32 + quad * 8;
      fah[t] = *(const short8*)(&sAh[ra]);
      fal[t] = *(const short8*)(&sAl[ra]);
      int rb = (wn * 64 + t * 16 + col) * 32 + quad * 8;
      fbh[t] = *(const short8*)(&sBh[rb]);
      fbl[t] = *(const short8*)(&sBl[rb]);
    }
#pragma unroll
    for (int tm = 0; tm < 4; ++tm)
#pragma unroll
      for (int tn = 0; tn < 4; ++tn) {
        acc[tm][tn] = __builtin_amdgcn_mfma_f32_16x16x32_bf16(fah[tm], fbh[tn], acc[tm][tn], 0, 0, 0);
        acc[tm][tn] = __builtin_amdgcn_mfma_f32_16x16x32_bf16(fah[tm], fbl[tn], acc[tm][tn], 0, 0, 0);
        acc[tm][tn] = __builtin_amdgcn_mfma_f32_16x16x32_bf16(fal[tm], fbh[tn], acc[tm][tn], 0, 0, 0);
      }
  }

  const int m_base = bm * 128 + wm * 64;
  const int n_base = bn * 128 + wn * 64;

  if (mode == 0) {
#pragma unroll
    for (int tm = 0; tm < 4; ++tm)
#pragma unroll
      for (int tn = 0; tn < 4; ++tn) {
        int gn = n_base + tn * 16 + col;
        float b = bias[gn];
#pragma unroll
        for (int rr = 0; rr < 4; ++rr) {
          int gm = m_base + tm * 16 + quad * 4 + rr;
          Cout[(size_t)gm * N + gn] = acc[tm][tn][rr] + b;
        }
      }
  } else {
    int reg = bn / 6;  // 0:Q 1:K 2:V (uniform per block)
    if (reg < 2) {
#pragma unroll
      for (int tm = 0; tm < 4; ++tm)
#pragma unroll
        for (int tn = 0; tn < 4; ++tn) {
          int el = (bn % 6) * 128 + wn * 64 + tn * 16 + col;  // 0..767
          int hh = el >> 6, dd = el & 63;
#pragma unroll
          for (int rr = 0; rr < 4; ++rr) {
            int gm = m_base + tm * 16 + quad * 4 + rr;
            float v = acc[tm][tn][rr];
            if (reg == 0) {
              v *= QSCALE;
              ushort hi = f2bf(v);
              size_t idx = ((size_t)hh * SEQ + gm) * HD + dd;  // Q unswizzled
              Qh[idx] = hi;
              Ql[idx] = f2bf(v - bf2f(hi));
            } else {
              // K swizzled: chunk' = chunk ^ (key&7) for attn's DMA image
              ushort hi = f2bf(v);
              int pc = ((dd >> 3) ^ (gm & 7)) & 7;
              size_t idx = ((size_t)hh * SEQ + gm) * HD + pc * 8 + (dd & 7);
              Kh[idx] = hi;
              Kl[idx] = f2bf(v - bf2f(hi));
            }
          }
        }
    } else {
      // ---- V: LDS transpose -> coalesced swizzled stores ----
      // Per-64-key-window swizzle: logical chunk c=(seq>>3)&7 stored at slot
      // c^(el&7); el&7 == dd&7, so LDS rows copy linearly to global.
      __syncthreads();
      ushort* vt_tile = smem;  // 128*128 ushort = 32KB
#pragma unroll
      for (int tm = 0; tm < 4; ++tm)
#pragma unroll
        for (int tn = 0; tn < 4; ++tn) {
          int el = wn * 64 + tn * 16 + col;
#pragma unroll
          for (int rr = 0; rr < 4; ++rr) {
            int seq = wm * 64 + tm * 16 + quad * 4 + rr;
            int cc = (((seq >> 3) & 7) ^ (el & 7)) & 7;
            vt_tile[el * 128 + (seq & 64) + cc * 8 + (seq & 7)] = f2bf(acc[tm][tn][rr]);
          }
        }
      __syncthreads();
      int el = tid >> 1;
      int elg = (bn % 6) * 128 + el;
      int hh = elg >> 6, dd = elg & 63;
      ushort* grow = Vt + (size_t)(hh * HD + dd) * SEQ + bm * 128;
#pragma unroll
      for (int i = 0; i < 8; ++i) {
        int c = ((tid & 1) * 8 + i + el) & 15;
        *(uint4*)(grow + c * 8) = *(const uint4*)(&vt_tile[el * 128 + c * 8]);
      }
    }
  }
}

// Flash attention R6: 128 q-rows/block (4 waves x 32 rows), double-buffered
// 64-key K/V DMA tiles. DMA for tile i+1 issued right after tile i's arrival
// barrier -> full compute phase to land, per-iter drain ~0 (R5: 32 full
// vmcnt(0) drains = ~35% stall). Staging traffic halves (each tile feeds 128
// rows). 384 blocks all co-resident. LDS 64KB -> 2 blocks/CU.
__global__ __launch_bounds__(256, 2) void attn_k(
    const ushort* __restrict__ Qh, const ushort* __restrict__ Ql,
    const ushort* __restrict__ Kh, const ushort* __restrict__ Kl,
    const ushort* __restrict__ Vt,
    ushort* __restrict__ Ch, ushort* __restrict__ Cl) {
  __shared__ ushort sKh[2][64 * 64];  // [key][chunk^key&7][8]
  __shared__ ushort sKl[2][64 * 64];
  __shared__ ushort sVt[2][64 * 64];  // [dim][chunk^dim&7][8]
  __shared__ ushort sP[4][32 * 64];   // per-wave, [row][chunk^row&7][8]

  const int tid = threadIdx.x, lane = tid & 63, w = tid >> 6;
  const int col = lane & 15, quad = lane >> 4;
  const int h = blockIdx.y;
  const int q0 = blockIdx.x * 128 + w * 32;

  // Q fragments: 2 row-tiles x 2 k-steps
  short8 fqh[2][2], fql[2][2];
#pragma unroll
  for (int sub = 0; sub < 2; ++sub)
#pragma unroll
    for (int ks = 0; ks < 2; ++ks) {
      size_t off = ((size_t)h * SEQ + q0 + sub * 16 + col) * HD + ks * 32 + quad * 8;
      fqh[sub][ks] = *(const short8*)(Qh + off);
      fql[sub][ks] = *(const short8*)(Ql + off);
    }

  float m2[8], ell[8];
  f32x4 o[2][4];
  const f32x4 zz = {0.f, 0.f, 0.f, 0.f};
#pragma unroll
  for (int i = 0; i < 8; ++i) { m2[i] = -1e30f; ell[i] = 0.f; }
#pragma unroll
  for (int sub = 0; sub < 2; ++sub)
#pragma unroll
    for (int td = 0; td < 4; ++td) o[sub][td] = zz;

  const ushort* khg = Kh + (size_t)h * SEQ * HD;  // swizzled [key][64]
  const ushort* klg = Kl + (size_t)h * SEQ * HD;
  const ushort* vtg = Vt + (size_t)h * HD * SEQ;  // swizzled [dim][SEQ]
  ushort* pw = &sP[w][0];

  // stage 64-key tile into buffer b: 24 x 1KB chunks, 6 per wave
#define STAGE(b, kb)                                                          \
  {                                                                           \
    _Pragma("unroll") for (int i = 0; i < 6; ++i) {                           \
      int idx = w * 6 + i;                                                    \
      int arr = idx >> 3, j = idx & 7;                                        \
      const ushort* g;                                                        \
      ushort* l;                                                              \
      if (arr == 0) {                                                         \
        g = khg + (size_t)((kb) + j * 8 + (lane >> 3)) * 64 + (lane & 7) * 8; \
        l = &sKh[b][j * 512];                                                 \
      } else if (arr == 1) {                                                  \
        g = klg + (size_t)((kb) + j * 8 + (lane >> 3)) * 64 + (lane & 7) * 8; \
        l = &sKl[b][j * 512];                                                 \
      } else {                                                                \
        g = vtg + (size_t)(j * 8 + (lane >> 3)) * SEQ + (kb) + (lane & 7) * 8;\
        l = &sVt[b][j * 512];                                                 \
      }                                                                       \
      __builtin_amdgcn_global_load_lds(                                       \
          (const GLOBAL_AS unsigned int*)g, (LDS_AS unsigned int*)l, 16, 0, 0);\
    }                                                                         \
  }

  STAGE(0, 0);
  int buf = 0;

  for (int kb = 0; kb < SEQ; kb += 64) {
    // wait own DMAs for current buffer; barrier makes all deposits visible
    asm volatile("s_waitcnt vmcnt(0)" ::: "memory");
    __syncthreads();
    if (kb + 64 < SEQ) STAGE(buf ^ 1, kb + 64);  // prefetch next tile

    const ushort* kh = &sKh[buf][0];
    const ushort* kl = &sKl[buf][0];
    const ushort* vt = &sVt[buf][0];

    // ---- scores: 2 row-subs x 4 key-tiles, 3-term split MFMA ----
    f32x4 s[2][4];
#pragma unroll
    for (int tn = 0; tn < 4; ++tn) {
      f32x4 a0 = zz, a1 = zz;
      const int rowb = (tn * 16 + col) * 64;
#pragma unroll
      for (int ks = 0; ks < 2; ++ks) {
        int slot = ((4 * ks + quad) ^ (col & 7)) & 7;
        short8 fkh = *(const short8*)(&kh[rowb + slot * 8]);
        short8 fkl = *(const short8*)(&kl[rowb + slot * 8]);
        a0 = __builtin_amdgcn_mfma_f32_16x16x32_bf16(fqh[0][ks], fkh, a0, 0, 0, 0);
        a0 = __builtin_amdgcn_mfma_f32_16x16x32_bf16(fqh[0][ks], fkl, a0, 0, 0, 0);
        a0 = __builtin_amdgcn_mfma_f32_16x16x32_bf16(fql[0][ks], fkh, a0, 0, 0, 0);
        a1 = __builtin_amdgcn_mfma_f32_16x16x32_bf16(fqh[1][ks], fkh, a1, 0, 0, 0);
        a1 = __builtin_amdgcn_mfma_f32_16x16x32_bf16(fqh[1][ks], fkl, a1, 0, 0, 0);
        a1 = __builtin_amdgcn_mfma_f32_16x16x32_bf16(fql[1][ks], fkh, a1, 0, 0, 0);
      }
      s[0][tn] = a0;
      s[1][tn] = a1;
    }

    // ---- online softmax (exp2 domain), 8 row-groups (sub,rr) ----
    float vm[8];
#pragma unroll
    for (int sub = 0; sub < 2; ++sub)
#pragma unroll
      for (int rr = 0; rr < 4; ++rr)
        vm[sub * 4 + rr] = fmaxf(fmaxf(s[sub][0][rr], s[sub][1][rr]),
                                 fmaxf(s[sub][2][rr], s[sub][3][rr]));
#pragma unroll
    for (int mk = 1; mk < 16; mk <<= 1)
#pragma unroll
      for (int g = 0; g < 8; ++g) vm[g] = fmaxf(vm[g], __shfl_xor(vm[g], mk, 64));

    float mn[8], alpha[8];
#pragma unroll
    for (int g = 0; g < 8; ++g) {
      mn[g] = fmaxf(m2[g], vm[g]);
      alpha[g] = exp2f(m2[g] - mn[g]);
      m2[g] = mn[g];
      ell[g] *= alpha[g];
    }
#pragma unroll
    for (int sub = 0; sub < 2; ++sub)
#pragma unroll
      for (int td = 0; td < 4; ++td)
#pragma unroll
        for (int rr = 0; rr < 4; ++rr) o[sub][td][rr] *= alpha[sub * 4 + rr];

    float rs[8] = {0.f, 0.f, 0.f, 0.f, 0.f, 0.f, 0.f, 0.f};
#pragma unroll
    for (int sub = 0; sub < 2; ++sub)
#pragma unroll
      for (int tn = 0; tn < 4; ++tn)
#pragma unroll
        for (int rr = 0; rr < 4; ++rr) {
          float p = exp2f(s[sub][tn][rr] - mn[sub * 4 + rr]);
          rs[sub * 4 + rr] += p;
          int row = sub * 16 + quad * 4 + rr;
          int slot = ((2 * tn + (col >> 3)) ^ (row & 7)) & 7;
          pw[row * 64 + slot * 8 + (col & 7)] = f2bf(p);
        }
#pragma unroll
    for (int mk = 1; mk < 16; mk <<= 1)
#pragma unroll
      for (int g = 0; g < 8; ++g) rs[g] += __shfl_xor(rs[g], mk, 64);
#pragma unroll
    for (int g = 0; g < 8; ++g) ell[g] += rs[g];

    // drain this wave's P writes before reading back (wave-private region)
    asm volatile("s_waitcnt lgkmcnt(0)" ::: "memory");

    short8 fp[2][2];
#pragma unroll
    for (int sub = 0; sub < 2; ++sub)
#pragma unroll
      for (int ks = 0; ks < 2; ++ks) {
        int slot = ((4 * ks + quad) ^ (col & 7)) & 7;
        fp[sub][ks] = *(const short8*)(pw + (sub * 16 + col) * 64 + slot * 8);
      }

#pragma unroll
    for (int td = 0; td < 4; ++td) {
#pragma unroll
      for (int ks = 0; ks < 2; ++ks) {
        int slot = ((4 * ks + quad) ^ (col & 7)) & 7;
        short8 fv = *(const short8*)(&vt[(td * 16 + col) * 64 + slot * 8]);
        o[0][td] = __builtin_amdgcn_mfma_f32_16x16x32_bf16(fp[0][ks], fv, o[0][td], 0, 0, 0);
        o[1][td] = __builtin_amdgcn_mfma_f32_16x16x32_bf16(fp[1][ks], fv, o[1][td], 0, 0, 0);
      }
    }
    buf ^= 1;
  }

  // epilogue: normalize, split to bf16 hi/lo ctx [4096][768]
#pragma unroll
  for (int sub = 0; sub < 2; ++sub)
#pragma unroll
    for (int td = 0; td < 4; ++td)
#pragma unroll
      for (int rr = 0; rr < 4; ++rr) {
        float v = o[sub][td][rr] / ell[sub * 4 + rr];
        int l = q0 + sub * 16 + quad * 4 + rr;
        int d = h * 64 + td * 16 + col;
        ushort hi = f2bf(v);
        size_t idx = (size_t)l * EMB + d;
        Ch[idx] = hi;
        Cl[idx] = f2bf(v - bf2f(hi));
      }
}

extern "C" void kernel_launch(void* const* d_in, const int* in_sizes, int n_in,
                              void* d_out, int out_size, void* d_ws, size_t ws_size,
                              hipStream_t stream) {
  const float* x = (const float*)d_in[0];       // [4096][768]
  const float* qkv_w = (const float*)d_in[1];   // [2304][768]
  const float* out_w = (const float*)d_in[2];   // [768][768]
  const float* out_b = (const float*)d_in[3];   // [768]
  float* out = (float*)d_out;                   // [4096][768]

  char* p = (char*)d_ws;
  auto carve = [&](size_t bytes) {
    char* q = p;
    p += (bytes + 255) & ~(size_t)255;
    return q;
  };
  const size_t NX = (size_t)SEQ * EMB;       // 3,145,728
  const size_t NQW = (size_t)3 * EMB * EMB;  // 1,769,472
  const size_t NOW = (size_t)EMB * EMB;      // 589,824
  const size_t NQKV = (size_t)NH * SEQ * HD; // 3,145,728

  ushort* xh = (ushort*)carve(NX * 2);
  ushort* xl = (ushort*)carve(NX * 2);
  ushort* qwh = (ushort*)carve(NQW * 2);
  ushort* qwl = (ushort*)carve(NQW * 2);
  ushort* owh = (ushort*)carve(NOW * 2);
  ushort* owl = (ushort*)carve(NOW * 2);
  ushort* Qh = (ushort*)carve(NQKV * 2);
  ushort* Ql = (ushort*)carve(NQKV * 2);
  ushort* Kh = (ushort*)carve(NQKV * 2);
  ushort* Kl = (ushort*)carve(NQKV * 2);
  ushort* Vt = (ushort*)carve(NQKV * 2);
  ushort* Ch = (ushort*)carve(NX * 2);
  ushort* Cl = (ushort*)carve(NX * 2);

  split_k<<<dim3((int)(NX / 256)), 256, 0, stream>>>(x, xh, xl, (int)NX);
  split_k<<<dim3((int)(NQW / 256)), 256, 0, stream>>>(qkv_w, qwh, qwl, (int)NQW);
  split_k<<<dim3((int)(NOW / 256)), 256, 0, stream>>>(out_w, owh, owl, (int)NOW);

  // QKV: M=4096, N=2304, K=768 -> scatter epilogue (K/V swizzled)
  gemm_bt_split<<<dim3(32, 18), 256, 0, stream>>>(
      xh, xl, qwh, qwl, SEQ, 3 * EMB, EMB, 1,
      nullptr, nullptr, Qh, Ql, Kh, Kl, Vt);

  attn_k<<<dim3(SEQ / 128, NH), 256, 0, stream>>>(Qh, Ql, Kh, Kl, Vt, Ch, Cl);

  // out proj: M=4096, N=768, K=768, + bias -> d_out
  gemm_bt_split<<<dim3(32, 6), 256, 0, stream>>>(
      Ch, Cl, owh, owl, SEQ, EMB, EMB, 0,
      out, out_b, nullptr, nullptr, nullptr, nullptr, nullptr);
}

// Round 7
// 417.691 us; speedup vs baseline: 1.0593x; 1.0593x over previous
//
#include <hip/hip_runtime.h>

typedef __attribute__((ext_vector_type(8))) short short8;
typedef __attribute__((ext_vector_type(4))) float f32x4;

#define EMB 768
#define SEQ 4096
#define NH 12
#define HD 64
// 8 * log2(e): folds the score scale AND the exp->exp2 conversion into Q
#define QSCALE 11.541560327111707f

#define GLOBAL_AS __attribute__((address_space(1)))
#define LDS_AS __attribute__((address_space(3)))

__device__ inline ushort f2bf(float v) {
  union { float f; unsigned int u; } x; x.f = v;
  unsigned int r = x.u + 0x7fffu + ((x.u >> 16) & 1u);
  return (ushort)(r >> 16);
}
__device__ inline float bf2f(ushort u) {
  union { float f; unsigned int u32; } x; x.u32 = ((unsigned int)u) << 16;
  return x.f;
}

__global__ void split_k(const float* __restrict__ src, ushort* __restrict__ hi,
                        ushort* __restrict__ lo, int n) {
  int i = blockIdx.x * blockDim.x + threadIdx.x;
  if (i < n) {
    float v = src[i];
    ushort h = f2bf(v);
    hi[i] = h;
    lo[i] = f2bf(v - bf2f(h));
  }
}

// C[m,n] = sum_k A[m,k]*B[n,k] (both K-contiguous), fp32-accurate via 3-term
// bf16 split MFMA, global_load_lds staging. mode 0: C += bias -> Cout fp32.
// mode 1: scatter QKV; V via LDS transpose -> coalesced swizzled stores.
// Vt swizzle is per-64-key window (chunk ^ dim&7) to match attn's 64-key
// double-buffered DMA tiles.
__global__ __launch_bounds__(256) void gemm_bt_split(
    const ushort* __restrict__ Ah, const ushort* __restrict__ Al,
    const ushort* __restrict__ Bh, const ushort* __restrict__ Bl,
    int M, int N, int K, int mode,
    float* __restrict__ Cout, const float* __restrict__ bias,
    ushort* __restrict__ Qh, ushort* __restrict__ Ql,
    ushort* __restrict__ Kh, ushort* __restrict__ Kl,
    ushort* __restrict__ Vt) {
  __shared__ ushort smem[4 * 128 * 32];
  ushort* sAh = smem;
  ushort* sAl = smem + 4096;
  ushort* sBh = smem + 8192;
  ushort* sBl = smem + 12288;

  const int tid = threadIdx.x;
  const int lane = tid & 63;
  const int w = tid >> 6;
  const int wm = w >> 1, wn = w & 1;
  const int col = lane & 15, quad = lane >> 4;
  const int bm = blockIdx.x, bn = blockIdx.y;

  const ushort* gsrc = (w == 0)   ? Ah + (size_t)bm * 128 * K
                       : (w == 1) ? Al + (size_t)bm * 128 * K
                       : (w == 2) ? Bh + (size_t)bn * 128 * K
                                  : Bl + (size_t)bn * 128 * K;
  ushort* lbase = (w == 0) ? sAh : (w == 1) ? sAl : (w == 2) ? sBh : sBl;
  const ushort* g0 = gsrc + (size_t)(lane >> 2) * K + (lane & 3) * 8;

  f32x4 acc[4][4];
  const f32x4 zz = {0.f, 0.f, 0.f, 0.f};
#pragma unroll
  for (int i = 0; i < 4; ++i)
#pragma unroll
    for (int j = 0; j < 4; ++j) acc[i][j] = zz;

  for (int kt = 0; kt < K; kt += 32) {
    __syncthreads();
#pragma unroll
    for (int i = 0; i < 8; ++i) {
      __builtin_amdgcn_global_load_lds(
          (const GLOBAL_AS unsigned int*)(g0 + (size_t)i * 16 * K + kt),
          (LDS_AS unsigned int*)(lbase + i * 512), 16, 0, 0);
    }
    asm volatile("s_waitcnt vmcnt(0)" ::: "memory");
    __syncthreads();

    short8 fah[4], fal[4], fbh[4], fbl[4];
#pragma unroll
    for (int t = 0; t < 4; ++t) {
      int ra = (wm * 64 + t * 16 + col) * 32 + quad * 8;
      fah[t] = *(const short8*)(&sAh[ra]);
      fal[t] = *(const short8*)(&sAl[ra]);
      int rb = (wn * 64 + t * 16 + col) * 32 + quad * 8;
      fbh[t] = *(const short8*)(&sBh[rb]);
      fbl[t] = *(const short8*)(&sBl[rb]);
    }
#pragma unroll
    for (int tm = 0; tm < 4; ++tm)
#pragma unroll
      for (int tn = 0; tn < 4; ++tn) {
        acc[tm][tn] = __builtin_amdgcn_mfma_f32_16x16x32_bf16(fah[tm], fbh[tn], acc[tm][tn], 0, 0, 0);
        acc[tm][tn] = __builtin_amdgcn_mfma_f32_16x16x32_bf16(fah[tm], fbl[tn], acc[tm][tn], 0, 0, 0);
        acc[tm][tn] = __builtin_amdgcn_mfma_f32_16x16x32_bf16(fal[tm], fbh[tn], acc[tm][tn], 0, 0, 0);
      }
  }

  const int m_base = bm * 128 + wm * 64;
  const int n_base = bn * 128 + wn * 64;

  if (mode == 0) {
#pragma unroll
    for (int tm = 0; tm < 4; ++tm)
#pragma unroll
      for (int tn = 0; tn < 4; ++tn) {
        int gn = n_base + tn * 16 + col;
        float b = bias[gn];
#pragma unroll
        for (int rr = 0; rr < 4; ++rr) {
          int gm = m_base + tm * 16 + quad * 4 + rr;
          Cout[(size_t)gm * N + gn] = acc[tm][tn][rr] + b;
        }
      }
  } else {
    int reg = bn / 6;  // 0:Q 1:K 2:V (uniform per block)
    if (reg < 2) {
#pragma unroll
      for (int tm = 0; tm < 4; ++tm)
#pragma unroll
        for (int tn = 0; tn < 4; ++tn) {
          int el = (bn % 6) * 128 + wn * 64 + tn * 16 + col;  // 0..767
          int hh = el >> 6, dd = el & 63;
#pragma unroll
          for (int rr = 0; rr < 4; ++rr) {
            int gm = m_base + tm * 16 + quad * 4 + rr;
            float v = acc[tm][tn][rr];
            if (reg == 0) {
              v *= QSCALE;
              ushort hi = f2bf(v);
              size_t idx = ((size_t)hh * SEQ + gm) * HD + dd;  // Q unswizzled
              Qh[idx] = hi;
              Ql[idx] = f2bf(v - bf2f(hi));
            } else {
              // K swizzled: chunk' = chunk ^ (key&7) for attn's DMA image
              ushort hi = f2bf(v);
              int pc = ((dd >> 3) ^ (gm & 7)) & 7;
              size_t idx = ((size_t)hh * SEQ + gm) * HD + pc * 8 + (dd & 7);
              Kh[idx] = hi;
              Kl[idx] = f2bf(v - bf2f(hi));
            }
          }
        }
    } else {
      // ---- V: LDS transpose -> coalesced swizzled stores ----
      // Per-64-key-window swizzle: logical chunk c=(seq>>3)&7 stored at slot
      // c^(el&7); el&7 == dd&7, so LDS rows copy linearly to global.
      __syncthreads();
      ushort* vt_tile = smem;  // 128*128 ushort = 32KB
#pragma unroll
      for (int tm = 0; tm < 4; ++tm)
#pragma unroll
        for (int tn = 0; tn < 4; ++tn) {
          int el = wn * 64 + tn * 16 + col;
#pragma unroll
          for (int rr = 0; rr < 4; ++rr) {
            int seq = wm * 64 + tm * 16 + quad * 4 + rr;
            int cc = (((seq >> 3) & 7) ^ (el & 7)) & 7;
            vt_tile[el * 128 + (seq & 64) + cc * 8 + (seq & 7)] = f2bf(acc[tm][tn][rr]);
          }
        }
      __syncthreads();
      int el = tid >> 1;
      int elg = (bn % 6) * 128 + el;
      int hh = elg >> 6, dd = elg & 63;
      ushort* grow = Vt + (size_t)(hh * HD + dd) * SEQ + bm * 128;
#pragma unroll
      for (int i = 0; i < 8; ++i) {
        int c = ((tid & 1) * 8 + i + el) & 15;
        *(uint4*)(grow + c * 8) = *(const uint4*)(&vt_tile[el * 128 + c * 8]);
      }
    }
  }
}

// Flash attention R7: back to 64 q-rows/block (768 blocks — R6's 384-block
// grid caused 2-vs-1 blocks/CU imbalance, occ 18->15%), KEEPING R6's
// double-buffered 64-key K/V DMA staging (the wait at iter top covers DMAs
// issued a full iteration earlier -> drain stall ~0). ell row-sum moved to an
// MFMA with B=ones (kills 16 shfl+16 add per iter on the VALU pipe).
// LDS 56KB -> 2 blocks/CU.
__global__ __launch_bounds__(256, 2) void attn_k(
    const ushort* __restrict__ Qh, const ushort* __restrict__ Ql,
    const ushort* __restrict__ Kh, const ushort* __restrict__ Kl,
    const ushort* __restrict__ Vt,
    ushort* __restrict__ Ch, ushort* __restrict__ Cl) {
  __shared__ ushort sKh[2][64 * 64];  // [key][chunk^key&7][8]
  __shared__ ushort sKl[2][64 * 64];
  __shared__ ushort sVt[2][64 * 64];  // [dim][chunk^dim&7][8]
  __shared__ ushort sP[4][16 * 64];   // per-wave, [row][chunk^row&7][8]

  const int tid = threadIdx.x, lane = tid & 63, w = tid >> 6;
  const int col = lane & 15, quad = lane >> 4;
  const int h = blockIdx.y;
  const int q0 = blockIdx.x * 64 + w * 16;

  const ushort* qh_base = Qh + ((size_t)h * SEQ + q0 + col) * HD;
  const ushort* ql_base = Ql + ((size_t)h * SEQ + q0 + col) * HD;
  short8 fqh[2], fql[2];
#pragma unroll
  for (int ks = 0; ks < 2; ++ks) {
    fqh[ks] = *(const short8*)(qh_base + ks * 32 + quad * 8);
    fql[ks] = *(const short8*)(ql_base + ks * 32 + quad * 8);
  }

  // bf16 1.0 fragment for the row-sum MFMA
  const short ONE = (short)0x3F80;
  const short8 ones = {ONE, ONE, ONE, ONE, ONE, ONE, ONE, ONE};

  float m2[4], ell[4];
  f32x4 o[4];
  const f32x4 zz = {0.f, 0.f, 0.f, 0.f};
#pragma unroll
  for (int i = 0; i < 4; ++i) { m2[i] = -1e30f; ell[i] = 0.f; o[i] = zz; }

  const ushort* khg = Kh + (size_t)h * SEQ * HD;  // swizzled [key][64]
  const ushort* klg = Kl + (size_t)h * SEQ * HD;
  const ushort* vtg = Vt + (size_t)h * HD * SEQ;  // swizzled [dim][SEQ]
  ushort* pw = &sP[w][0];

  // stage 64-key tile into buffer b: 24 x 1KB chunks, 6 per wave
#define STAGE(b, kb)                                                          \
  {                                                                           \
    _Pragma("unroll") for (int i = 0; i < 6; ++i) {                           \
      int idx = w * 6 + i;                                                    \
      int arr = idx >> 3, j = idx & 7;                                        \
      const ushort* g;                                                        \
      ushort* l;                                                              \
      if (arr == 0) {                                                         \
        g = khg + (size_t)((kb) + j * 8 + (lane >> 3)) * 64 + (lane & 7) * 8; \
        l = &sKh[b][j * 512];                                                 \
      } else if (arr == 1) {                                                  \
        g = klg + (size_t)((kb) + j * 8 + (lane >> 3)) * 64 + (lane & 7) * 8; \
        l = &sKl[b][j * 512];                                                 \
      } else {                                                                \
        g = vtg + (size_t)(j * 8 + (lane >> 3)) * SEQ + (kb) + (lane & 7) * 8;\
        l = &sVt[b][j * 512];                                                 \
      }                                                                       \
      __builtin_amdgcn_global_load_lds(                                       \
          (const GLOBAL_AS unsigned int*)g, (LDS_AS unsigned int*)l, 16, 0, 0);\
    }                                                                         \
  }

  STAGE(0, 0);
  int buf = 0;

  for (int kb = 0; kb < SEQ; kb += 64) {
    // wait own DMAs (issued one iteration ago) + make all deposits visible
    asm volatile("s_waitcnt vmcnt(0)" ::: "memory");
    __syncthreads();
    if (kb + 64 < SEQ) STAGE(buf ^ 1, kb + 64);  // lands during this compute

    const ushort* kh = &sKh[buf][0];
    const ushort* kl = &sKl[buf][0];
    const ushort* vt = &sVt[buf][0];

    // ---- scores: 4 key-tiles of 16, 3-term split MFMA ----
    f32x4 s[4];
#pragma unroll
    for (int tn = 0; tn < 4; ++tn) {
      f32x4 a = zz;
      const int rowb = (tn * 16 + col) * 64;
#pragma unroll
      for (int ks = 0; ks < 2; ++ks) {
        int slot = ((4 * ks + quad) ^ (col & 7)) & 7;
        short8 fkh = *(const short8*)(&kh[rowb + slot * 8]);
        short8 fkl = *(const short8*)(&kl[rowb + slot * 8]);
        a = __builtin_amdgcn_mfma_f32_16x16x32_bf16(fqh[ks], fkh, a, 0, 0, 0);
        a = __builtin_amdgcn_mfma_f32_16x16x32_bf16(fqh[ks], fkl, a, 0, 0, 0);
        a = __builtin_amdgcn_mfma_f32_16x16x32_bf16(fql[ks], fkh, a, 0, 0, 0);
      }
      s[tn] = a;
    }

    // ---- online softmax (exp2 domain) ----
    float vm[4];
#pragma unroll
    for (int rr = 0; rr < 4; ++rr)
      vm[rr] = fmaxf(fmaxf(s[0][rr], s[1][rr]), fmaxf(s[2][rr], s[3][rr]));
#pragma unroll
    for (int mk = 1; mk < 16; mk <<= 1)
#pragma unroll
      for (int rr = 0; rr < 4; ++rr) vm[rr] = fmaxf(vm[rr], __shfl_xor(vm[rr], mk, 64));

    float mn[4], alpha[4];
#pragma unroll
    for (int rr = 0; rr < 4; ++rr) {
      mn[rr] = fmaxf(m2[rr], vm[rr]);
      alpha[rr] = exp2f(m2[rr] - mn[rr]);
      m2[rr] = mn[rr];
      ell[rr] *= alpha[rr];
    }
#pragma unroll
    for (int td = 0; td < 4; ++td)
#pragma unroll
      for (int rr = 0; rr < 4; ++rr) o[td][rr] *= alpha[rr];

#pragma unroll
    for (int tn = 0; tn < 4; ++tn)
#pragma unroll
      for (int rr = 0; rr < 4; ++rr) {
        float p = exp2f(s[tn][rr] - mn[rr]);
        int row = quad * 4 + rr;
        int slot = ((2 * tn + (col >> 3)) ^ (row & 7)) & 7;
        pw[row * 64 + slot * 8 + (col & 7)] = f2bf(p);
      }

    // drain this wave's P writes before reading back (wave-private region)
    asm volatile("s_waitcnt lgkmcnt(0)" ::: "memory");

    short8 fp[2];
#pragma unroll
    for (int ks = 0; ks < 2; ++ks) {
      int slot = ((4 * ks + quad) ^ (col & 7)) & 7;
      fp[ks] = *(const short8*)(pw + col * 64 + slot * 8);
    }

    // row-sum of P via MFMA with B=ones (replaces 16 shfl + 16 add)
    f32x4 psum = zz;
    psum = __builtin_amdgcn_mfma_f32_16x16x32_bf16(fp[0], ones, psum, 0, 0, 0);
    psum = __builtin_amdgcn_mfma_f32_16x16x32_bf16(fp[1], ones, psum, 0, 0, 0);
#pragma unroll
    for (int rr = 0; rr < 4; ++rr) ell[rr] += psum[rr];

#pragma unroll
    for (int td = 0; td < 4; ++td) {
#pragma unroll
      for (int ks = 0; ks < 2; ++ks) {
        int slot = ((4 * ks + quad) ^ (col & 7)) & 7;
        short8 fv = *(const short8*)(&vt[(td * 16 + col) * 64 + slot * 8]);
        o[td] = __builtin_amdgcn_mfma_f32_16x16x32_bf16(fp[ks], fv, o[td], 0, 0, 0);
      }
    }
    buf ^= 1;
  }

  // epilogue: normalize, split to bf16 hi/lo ctx [4096][768]
#pragma unroll
  for (int td = 0; td < 4; ++td)
#pragma unroll
    for (int rr = 0; rr < 4; ++rr) {
      float v = o[td][rr] / ell[rr];
      int l = q0 + quad * 4 + rr;
      int d = h * 64 + td * 16 + col;
      ushort hi = f2bf(v);
      size_t idx = (size_t)l * EMB + d;
      Ch[idx] = hi;
      Cl[idx] = f2bf(v - bf2f(hi));
    }
}

extern "C" void kernel_launch(void* const* d_in, const int* in_sizes, int n_in,
                              void* d_out, int out_size, void* d_ws, size_t ws_size,
                              hipStream_t stream) {
  const float* x = (const float*)d_in[0];       // [4096][768]
  const float* qkv_w = (const float*)d_in[1];   // [2304][768]
  const float* out_w = (const float*)d_in[2];   // [768][768]
  const float* out_b = (const float*)d_in[3];   // [768]
  float* out = (float*)d_out;                   // [4096][768]

  char* p = (char*)d_ws;
  auto carve = [&](size_t bytes) {
    char* q = p;
    p += (bytes + 255) & ~(size_t)255;
    return q;
  };
  const size_t NX = (size_t)SEQ * EMB;       // 3,145,728
  const size_t NQW = (size_t)3 * EMB * EMB;  // 1,769,472
  const size_t NOW = (size_t)EMB * EMB;      // 589,824
  const size_t NQKV = (size_t)NH * SEQ * HD; // 3,145,728

  ushort* xh = (ushort*)carve(NX * 2);
  ushort* xl = (ushort*)carve(NX * 2);
  ushort* qwh = (ushort*)carve(NQW * 2);
  ushort* qwl = (ushort*)carve(NQW * 2);
  ushort* owh = (ushort*)carve(NOW * 2);
  ushort* owl = (ushort*)carve(NOW * 2);
  ushort* Qh = (ushort*)carve(NQKV * 2);
  ushort* Ql = (ushort*)carve(NQKV * 2);
  ushort* Kh = (ushort*)carve(NQKV * 2);
  ushort* Kl = (ushort*)carve(NQKV * 2);
  ushort* Vt = (ushort*)carve(NQKV * 2);
  ushort* Ch = (ushort*)carve(NX * 2);
  ushort* Cl = (ushort*)carve(NX * 2);

  split_k<<<dim3((int)(NX / 256)), 256, 0, stream>>>(x, xh, xl, (int)NX);
  split_k<<<dim3((int)(NQW / 256)), 256, 0, stream>>>(qkv_w, qwh, qwl, (int)NQW);
  split_k<<<dim3((int)(NOW / 256)), 256, 0, stream>>>(out_w, owh, owl, (int)NOW);

  // QKV: M=4096, N=2304, K=768 -> scatter epilogue (K/V swizzled)
  gemm_bt_split<<<dim3(32, 18), 256, 0, stream>>>(
      xh, xl, qwh, qwl, SEQ, 3 * EMB, EMB, 1,
      nullptr, nullptr, Qh, Ql, Kh, Kl, Vt);

  attn_k<<<dim3(SEQ / 64, NH), 256, 0, stream>>>(Qh, Ql, Kh, Kl, Vt, Ch, Cl);

  // out proj: M=4096, N=768, K=768, + bias -> d_out
  gemm_bt_split<<<dim3(32, 6), 256, 0, stream>>>(
      Ch, Cl, owh, owl, SEQ, EMB, EMB, 0,
      out, out_b, nullptr, nullptr, nullptr, nullptr, nullptr);
}

// Round 8
// 337.740 us; speedup vs baseline: 1.3100x; 1.2367x over previous
//
#include <hip/hip_runtime.h>

typedef __attribute__((ext_vector_type(8))) short short8;
typedef __attribute__((ext_vector_type(4))) float f32x4;

#define EMB 768
#define SEQ 4096
#define NH 12
#define HD 64
// 8 * log2(e): folds the score scale AND the exp->exp2 conversion into Q
#define QSCALE 11.541560327111707f

#define GLOBAL_AS __attribute__((address_space(1)))
#define LDS_AS __attribute__((address_space(3)))

__device__ inline ushort f2bf(float v) {
  union { float f; unsigned int u; } x; x.f = v;
  unsigned int r = x.u + 0x7fffu + ((x.u >> 16) & 1u);
  return (ushort)(r >> 16);
}
__device__ inline float bf2f(ushort u) {
  union { float f; unsigned int u32; } x; x.u32 = ((unsigned int)u) << 16;
  return x.f;
}

// 16-lane max reduction on the VALU via DPP (no LDS pipe, no shuffle latency):
// xor1, xor2 via quad_perm; then row_ror:4 and row_ror:8 complete the 16-lane row.
__device__ inline float dpp_max16(float v) {
  int t;
  t = __builtin_amdgcn_update_dpp(0, __float_as_int(v), 0xB1, 0xf, 0xf, true);   // quad_perm(1,0,3,2)
  v = fmaxf(v, __int_as_float(t));
  t = __builtin_amdgcn_update_dpp(0, __float_as_int(v), 0x4E, 0xf, 0xf, true);   // quad_perm(2,3,0,1)
  v = fmaxf(v, __int_as_float(t));
  t = __builtin_amdgcn_update_dpp(0, __float_as_int(v), 0x124, 0xf, 0xf, true);  // row_ror:4
  v = fmaxf(v, __int_as_float(t));
  t = __builtin_amdgcn_update_dpp(0, __float_as_int(v), 0x128, 0xf, 0xf, true);  // row_ror:8
  v = fmaxf(v, __int_as_float(t));
  return v;
}

__global__ void split_k(const float* __restrict__ src, ushort* __restrict__ hi,
                        ushort* __restrict__ lo, int n) {
  int i = blockIdx.x * blockDim.x + threadIdx.x;
  if (i < n) {
    float v = src[i];
    ushort h = f2bf(v);
    hi[i] = h;
    lo[i] = f2bf(v - bf2f(h));
  }
}

// C[m,n] = sum_k A[m,k]*B[n,k] (both K-contiguous), fp32-accurate via 3-term
// bf16 split MFMA, global_load_lds staging. mode 0: C += bias -> Cout fp32.
// mode 1: scatter QKV; V via LDS transpose -> coalesced swizzled stores.
__global__ __launch_bounds__(256) void gemm_bt_split(
    const ushort* __restrict__ Ah, const ushort* __restrict__ Al,
    const ushort* __restrict__ Bh, const ushort* __restrict__ Bl,
    int M, int N, int K, int mode,
    float* __restrict__ Cout, const float* __restrict__ bias,
    ushort* __restrict__ Qh, ushort* __restrict__ Ql,
    ushort* __restrict__ Kh, ushort* __restrict__ Kl,
    ushort* __restrict__ Vt) {
  __shared__ ushort smem[4 * 128 * 32];
  ushort* sAh = smem;
  ushort* sAl = smem + 4096;
  ushort* sBh = smem + 8192;
  ushort* sBl = smem + 12288;

  const int tid = threadIdx.x;
  const int lane = tid & 63;
  const int w = tid >> 6;
  const int wm = w >> 1, wn = w & 1;
  const int col = lane & 15, quad = lane >> 4;
  const int bm = blockIdx.x, bn = blockIdx.y;

  const ushort* gsrc = (w == 0)   ? Ah + (size_t)bm * 128 * K
                       : (w == 1) ? Al + (size_t)bm * 128 * K
                       : (w == 2) ? Bh + (size_t)bn * 128 * K
                                  : Bl + (size_t)bn * 128 * K;
  ushort* lbase = (w == 0) ? sAh : (w == 1) ? sAl : (w == 2) ? sBh : sBl;
  const ushort* g0 = gsrc + (size_t)(lane >> 2) * K + (lane & 3) * 8;

  f32x4 acc[4][4];
  const f32x4 zz = {0.f, 0.f, 0.f, 0.f};
#pragma unroll
  for (int i = 0; i < 4; ++i)
#pragma unroll
    for (int j = 0; j < 4; ++j) acc[i][j] = zz;

  for (int kt = 0; kt < K; kt += 32) {
    __syncthreads();
#pragma unroll
    for (int i = 0; i < 8; ++i) {
      __builtin_amdgcn_global_load_lds(
          (const GLOBAL_AS unsigned int*)(g0 + (size_t)i * 16 * K + kt),
          (LDS_AS unsigned int*)(lbase + i * 512), 16, 0, 0);
    }
    asm volatile("s_waitcnt vmcnt(0)" ::: "memory");
    __syncthreads();

    short8 fah[4], fal[4], fbh[4], fbl[4];
#pragma unroll
    for (int t = 0; t < 4; ++t) {
      int ra = (wm * 64 + t * 16 + col) * 32 + quad * 8;
      fah[t] = *(const short8*)(&sAh[ra]);
      fal[t] = *(const short8*)(&sAl[ra]);
      int rb = (wn * 64 + t * 16 + col) * 32 + quad * 8;
      fbh[t] = *(const short8*)(&sBh[rb]);
      fbl[t] = *(const short8*)(&sBl[rb]);
    }
#pragma unroll
    for (int tm = 0; tm < 4; ++tm)
#pragma unroll
      for (int tn = 0; tn < 4; ++tn) {
        acc[tm][tn] = __builtin_amdgcn_mfma_f32_16x16x32_bf16(fah[tm], fbh[tn], acc[tm][tn], 0, 0, 0);
        acc[tm][tn] = __builtin_amdgcn_mfma_f32_16x16x32_bf16(fah[tm], fbl[tn], acc[tm][tn], 0, 0, 0);
        acc[tm][tn] = __builtin_amdgcn_mfma_f32_16x16x32_bf16(fal[tm], fbh[tn], acc[tm][tn], 0, 0, 0);
      }
  }

  const int m_base = bm * 128 + wm * 64;
  const int n_base = bn * 128 + wn * 64;

  if (mode == 0) {
#pragma unroll
    for (int tm = 0; tm < 4; ++tm)
#pragma unroll
      for (int tn = 0; tn < 4; ++tn) {
        int gn = n_base + tn * 16 + col;
        float b = bias[gn];
#pragma unroll
        for (int rr = 0; rr < 4; ++rr) {
          int gm = m_base + tm * 16 + quad * 4 + rr;
          Cout[(size_t)gm * N + gn] = acc[tm][tn][rr] + b;
        }
      }
  } else {
    int reg = bn / 6;  // 0:Q 1:K 2:V (uniform per block)
    if (reg < 2) {
#pragma unroll
      for (int tm = 0; tm < 4; ++tm)
#pragma unroll
        for (int tn = 0; tn < 4; ++tn) {
          int el = (bn % 6) * 128 + wn * 64 + tn * 16 + col;  // 0..767
          int hh = el >> 6, dd = el & 63;
#pragma unroll
          for (int rr = 0; rr < 4; ++rr) {
            int gm = m_base + tm * 16 + quad * 4 + rr;
            float v = acc[tm][tn][rr];
            if (reg == 0) {
              v *= QSCALE;
              ushort hi = f2bf(v);
              size_t idx = ((size_t)hh * SEQ + gm) * HD + dd;  // Q unswizzled
              Qh[idx] = hi;
              Ql[idx] = f2bf(v - bf2f(hi));
            } else {
              // K swizzled: chunk' = chunk ^ (key&7) for attn's DMA image
              ushort hi = f2bf(v);
              int pc = ((dd >> 3) ^ (gm & 7)) & 7;
              size_t idx = ((size_t)hh * SEQ + gm) * HD + pc * 8 + (dd & 7);
              Kh[idx] = hi;
              Kl[idx] = f2bf(v - bf2f(hi));
            }
          }
        }
    } else {
      // ---- V: LDS transpose -> coalesced swizzled stores ----
      __syncthreads();
      ushort* vt_tile = smem;  // 128*128 ushort = 32KB
#pragma unroll
      for (int tm = 0; tm < 4; ++tm)
#pragma unroll
        for (int tn = 0; tn < 4; ++tn) {
          int el = wn * 64 + tn * 16 + col;
#pragma unroll
          for (int rr = 0; rr < 4; ++rr) {
            int seq = wm * 64 + tm * 16 + quad * 4 + rr;
            int cc = (((seq >> 3) & 7) ^ (el & 7)) & 7;
            vt_tile[el * 128 + (seq & 64) + cc * 8 + (seq & 7)] = f2bf(acc[tm][tn][rr]);
          }
        }
      __syncthreads();
      int el = tid >> 1;
      int elg = (bn % 6) * 128 + el;
      int hh = elg >> 6, dd = elg & 63;
      ushort* grow = Vt + (size_t)(hh * HD + dd) * SEQ + bm * 128;
#pragma unroll
      for (int i = 0; i < 8; ++i) {
        int c = ((tid & 1) * 8 + i + el) & 15;
        *(uint4*)(grow + c * 8) = *(const uint4*)(&vt_tile[el * 128 + c * 8]);
      }
    }
  }
}

// Flash attention R8: 64 q-rows/block, 64-key double-buffered DMA tiles
// (R7 structure) + 3 blocks/CU (52KB LDS: P processed in 32-key halves),
// DPP-based max reduce (VALU, kills the LDS-shuffle serial chain), truncating
// P pack (ell = MFMA rowsum of stored P -> normalization exact), hoisted LDS
// offsets + pointer-incremented staging.
__global__ __launch_bounds__(256, 3) void attn_k(
    const ushort* __restrict__ Qh, const ushort* __restrict__ Ql,
    const ushort* __restrict__ Kh, const ushort* __restrict__ Kl,
    const ushort* __restrict__ Vt,
    ushort* __restrict__ Ch, ushort* __restrict__ Cl) {
  __shared__ ushort sKh[2][64 * 64];  // [key][chunk^key&7][8]
  __shared__ ushort sKl[2][64 * 64];
  __shared__ ushort sVt[2][64 * 64];  // [dim][chunk^dim&7][8]
  __shared__ ushort sP[4][16 * 32];   // per-wave 32-key half; slot = chunk^ (row&3) ^ (row>>2)

  const int tid = threadIdx.x, lane = tid & 63, w = tid >> 6;
  const int col = lane & 15, quad = lane >> 4;
  const int h = blockIdx.y;
  const int q0 = blockIdx.x * 64 + w * 16;

  const ushort* qh_base = Qh + ((size_t)h * SEQ + q0 + col) * HD;
  const ushort* ql_base = Ql + ((size_t)h * SEQ + q0 + col) * HD;
  short8 fqh[2], fql[2];
#pragma unroll
  for (int ks = 0; ks < 2; ++ks) {
    fqh[ks] = *(const short8*)(qh_base + ks * 32 + quad * 8);
    fql[ks] = *(const short8*)(ql_base + ks * 32 + quad * 8);
  }

  const short ONE = (short)0x3F80;
  const short8 ones = {ONE, ONE, ONE, ONE, ONE, ONE, ONE, ONE};

  float m2[4], ell[4];
  f32x4 o[4];
  const f32x4 zz = {0.f, 0.f, 0.f, 0.f};
#pragma unroll
  for (int i = 0; i < 4; ++i) { m2[i] = -1e30f; ell[i] = 0.f; o[i] = zz; }

  const ushort* khg = Kh + (size_t)h * SEQ * HD;  // swizzled [key][64]
  const ushort* klg = Kl + (size_t)h * SEQ * HD;
  const ushort* vtg = Vt + (size_t)h * HD * SEQ;  // swizzled [dim][SEQ]
  ushort* pw = &sP[w][0];

  // staging pointers: wave w owns chunks idx = w*6 .. w*6+5; advance per iter
  const ushort* gp[6];
  ushort* lp[6];
  int gstep[6];
#pragma unroll
  for (int i = 0; i < 6; ++i) {
    int idx = w * 6 + i;
    int arr = idx >> 3, j = idx & 7;
    if (arr == 0) {
      gp[i] = khg + (size_t)(j * 8 + (lane >> 3)) * 64 + (lane & 7) * 8;
      lp[i] = &sKh[0][j * 512];
      gstep[i] = 64 * 64;
    } else if (arr == 1) {
      gp[i] = klg + (size_t)(j * 8 + (lane >> 3)) * 64 + (lane & 7) * 8;
      lp[i] = &sKl[0][j * 512];
      gstep[i] = 64 * 64;
    } else {
      gp[i] = vtg + (size_t)(j * 8 + (lane >> 3)) * SEQ + (lane & 7) * 8;
      lp[i] = &sVt[0][j * 512];
      gstep[i] = 64;
    }
  }

  // initial stage into buf 0
#pragma unroll
  for (int i = 0; i < 6; ++i) {
    __builtin_amdgcn_global_load_lds((const GLOBAL_AS unsigned int*)gp[i],
                                     (LDS_AS unsigned int*)lp[i], 16, 0, 0);
    gp[i] += gstep[i];
  }

  // loop-invariant LDS byte offsets
  const int koff0 = (col * 64 + ((quad ^ (col & 7)) & 7) * 8) * 2;        // ks=0
  const int koff1 = (col * 64 + (((4 + quad) ^ (col & 7)) & 7) * 8) * 2;  // ks=1
  const int fpoff = (col * 32 + ((quad ^ (col & 3) ^ ((col >> 2) & 3)) & 3) * 8) * 2;
  const int voff0 = koff0;  // vt uses same (col,quad) swizzle pattern, hh=0
  const int voff1 = koff1;  // hh=1

  auto do_iter = [&](int buf) {
    // wait own DMAs (issued one iteration ago); barrier makes all visible
    asm volatile("s_waitcnt vmcnt(0)" ::: "memory");
    __syncthreads();
    // prefetch next tile into buf^1 (lands during this iteration's compute)
#pragma unroll
    for (int i = 0; i < 6; ++i) {
      __builtin_amdgcn_global_load_lds(
          (const GLOBAL_AS unsigned int*)gp[i],
          (LDS_AS unsigned int*)(lp[i] + (buf ^ 1) * 4096), 16, 0, 0);
      gp[i] += gstep[i];
    }
    const char* kh = (const char*)&sKh[buf][0];
    const char* kl = (const char*)&sKl[buf][0];
    const char* vt = (const char*)&sVt[buf][0];

    // ---- scores: 4 key-tiles of 16, 3-term split MFMA ----
    f32x4 s[4];
#pragma unroll
    for (int tn = 0; tn < 4; ++tn) {
      f32x4 a = zz;
      short8 kh0 = *(const short8*)(kh + tn * 2048 + koff0);
      short8 kl0 = *(const short8*)(kl + tn * 2048 + koff0);
      short8 kh1 = *(const short8*)(kh + tn * 2048 + koff1);
      short8 kl1 = *(const short8*)(kl + tn * 2048 + koff1);
      a = __builtin_amdgcn_mfma_f32_16x16x32_bf16(fqh[0], kh0, a, 0, 0, 0);
      a = __builtin_amdgcn_mfma_f32_16x16x32_bf16(fqh[0], kl0, a, 0, 0, 0);
      a = __builtin_amdgcn_mfma_f32_16x16x32_bf16(fql[0], kh0, a, 0, 0, 0);
      a = __builtin_amdgcn_mfma_f32_16x16x32_bf16(fqh[1], kh1, a, 0, 0, 0);
      a = __builtin_amdgcn_mfma_f32_16x16x32_bf16(fqh[1], kl1, a, 0, 0, 0);
      a = __builtin_amdgcn_mfma_f32_16x16x32_bf16(fql[1], kh1, a, 0, 0, 0);
      s[tn] = a;
    }

    // ---- online softmax (exp2 domain); DPP max reduce on the VALU ----
    float mn[4], alpha[4];
#pragma unroll
    for (int rr = 0; rr < 4; ++rr) {
      float vm = fmaxf(fmaxf(s[0][rr], s[1][rr]), fmaxf(s[2][rr], s[3][rr]));
      vm = dpp_max16(vm);
      mn[rr] = fmaxf(m2[rr], vm);
      alpha[rr] = exp2f(m2[rr] - mn[rr]);
      m2[rr] = mn[rr];
      ell[rr] *= alpha[rr];
    }
#pragma unroll
    for (int td = 0; td < 4; ++td)
#pragma unroll
      for (int rr = 0; rr < 4; ++rr) o[td][rr] *= alpha[rr];

    // ---- P in 32-key halves: write (trunc pack), rowsum MFMA, PV ----
    f32x4 psum = zz;
#pragma unroll
    for (int hh = 0; hh < 2; ++hh) {
#pragma unroll
      for (int t2 = 0; t2 < 2; ++t2) {
        int tn = hh * 2 + t2;
#pragma unroll
        for (int rr = 0; rr < 4; ++rr) {
          float p = exp2f(s[tn][rr] - mn[rr]);
          int row = quad * 4 + rr;
          int cc = t2 * 16 + col;
          int slot = ((cc >> 3) ^ rr ^ quad) & 3;
          pw[row * 32 + slot * 8 + (cc & 7)] =
              (ushort)(__float_as_uint(p) >> 16);  // trunc: ell uses stored P
        }
      }
      // drain this wave's P writes (wave-private region; DS ops in-order)
      asm volatile("s_waitcnt lgkmcnt(0)" ::: "memory");
      short8 fp = *(const short8*)((const char*)pw + fpoff);
      psum = __builtin_amdgcn_mfma_f32_16x16x32_bf16(fp, ones, psum, 0, 0, 0);
      const int vo = hh ? voff1 : voff0;
#pragma unroll
      for (int td = 0; td < 4; ++td) {
        short8 fv = *(const short8*)(vt + td * 2048 + vo);
        o[td] = __builtin_amdgcn_mfma_f32_16x16x32_bf16(fp, fv, o[td], 0, 0, 0);
      }
    }
#pragma unroll
    for (int rr = 0; rr < 4; ++rr) ell[rr] += psum[rr];
  };

  for (int kb = 0; kb < SEQ; kb += 128) {
    do_iter(0);
    do_iter(1);
  }

  // epilogue: normalize, split to bf16 hi/lo ctx [4096][768]
#pragma unroll
  for (int td = 0; td < 4; ++td)
#pragma unroll
    for (int rr = 0; rr < 4; ++rr) {
      float v = o[td][rr] / ell[rr];
      int l = q0 + quad * 4 + rr;
      int d = h * 64 + td * 16 + col;
      ushort hi = f2bf(v);
      size_t idx = (size_t)l * EMB + d;
      Ch[idx] = hi;
      Cl[idx] = f2bf(v - bf2f(hi));
    }
}

extern "C" void kernel_launch(void* const* d_in, const int* in_sizes, int n_in,
                              void* d_out, int out_size, void* d_ws, size_t ws_size,
                              hipStream_t stream) {
  const float* x = (const float*)d_in[0];       // [4096][768]
  const float* qkv_w = (const float*)d_in[1];   // [2304][768]
  const float* out_w = (const float*)d_in[2];   // [768][768]
  const float* out_b = (const float*)d_in[3];   // [768]
  float* out = (float*)d_out;                   // [4096][768]

  char* p = (char*)d_ws;
  auto carve = [&](size_t bytes) {
    char* q = p;
    p += (bytes + 255) & ~(size_t)255;
    return q;
  };
  const size_t NX = (size_t)SEQ * EMB;       // 3,145,728
  const size_t NQW = (size_t)3 * EMB * EMB;  // 1,769,472
  const size_t NOW = (size_t)EMB * EMB;      // 589,824
  const size_t NQKV = (size_t)NH * SEQ * HD; // 3,145,728

  ushort* xh = (ushort*)carve(NX * 2);
  ushort* xl = (ushort*)carve(NX * 2);
  ushort* qwh = (ushort*)carve(NQW * 2);
  ushort* qwl = (ushort*)carve(NQW * 2);
  ushort* owh = (ushort*)carve(NOW * 2);
  ushort* owl = (ushort*)carve(NOW * 2);
  ushort* Qh = (ushort*)carve(NQKV * 2);
  ushort* Ql = (ushort*)carve(NQKV * 2);
  ushort* Kh = (ushort*)carve(NQKV * 2);
  ushort* Kl = (ushort*)carve(NQKV * 2);
  ushort* Vt = (ushort*)carve(NQKV * 2);
  ushort* Ch = (ushort*)carve(NX * 2);
  ushort* Cl = (ushort*)carve(NX * 2);

  split_k<<<dim3((int)(NX / 256)), 256, 0, stream>>>(x, xh, xl, (int)NX);
  split_k<<<dim3((int)(NQW / 256)), 256, 0, stream>>>(qkv_w, qwh, qwl, (int)NQW);
  split_k<<<dim3((int)(NOW / 256)), 256, 0, stream>>>(out_w, owh, owl, (int)NOW);

  // QKV: M=4096, N=2304, K=768 -> scatter epilogue (K/V swizzled)
  gemm_bt_split<<<dim3(32, 18), 256, 0, stream>>>(
      xh, xl, qwh, qwl, SEQ, 3 * EMB, EMB, 1,
      nullptr, nullptr, Qh, Ql, Kh, Kl, Vt);

  attn_k<<<dim3(SEQ / 64, NH), 256, 0, stream>>>(Qh, Ql, Kh, Kl, Vt, Ch, Cl);

  // out proj: M=4096, N=768, K=768, + bias -> d_out
  gemm_bt_split<<<dim3(32, 6), 256, 0, stream>>>(
      Ch, Cl, owh, owl, SEQ, EMB, EMB, 0,
      out, out_b, nullptr, nullptr, nullptr, nullptr, nullptr);
}

// Round 9
// 321.654 us; speedup vs baseline: 1.3755x; 1.0500x over previous
//
#include <hip/hip_runtime.h>

typedef __attribute__((ext_vector_type(8))) short short8;
typedef __attribute__((ext_vector_type(4))) float f32x4;

#define EMB 768
#define SEQ 4096
#define NH 12
#define HD 64
// 8 * log2(e): folds the score scale AND the exp->exp2 conversion into Q
#define QSCALE 11.541560327111707f

#define GLOBAL_AS __attribute__((address_space(1)))
#define LDS_AS __attribute__((address_space(3)))

__device__ inline ushort f2bf(float v) {
  union { float f; unsigned int u; } x; x.f = v;
  unsigned int r = x.u + 0x7fffu + ((x.u >> 16) & 1u);
  return (ushort)(r >> 16);
}
__device__ inline float bf2f(ushort u) {
  union { float f; unsigned int u32; } x; x.u32 = ((unsigned int)u) << 16;
  return x.f;
}

// 16-lane max reduction on the VALU via DPP (no LDS pipe, no shuffle latency).
__device__ inline float dpp_max16(float v) {
  int t;
  t = __builtin_amdgcn_update_dpp(0, __float_as_int(v), 0xB1, 0xf, 0xf, true);   // quad_perm(1,0,3,2)
  v = fmaxf(v, __int_as_float(t));
  t = __builtin_amdgcn_update_dpp(0, __float_as_int(v), 0x4E, 0xf, 0xf, true);   // quad_perm(2,3,0,1)
  v = fmaxf(v, __int_as_float(t));
  t = __builtin_amdgcn_update_dpp(0, __float_as_int(v), 0x124, 0xf, 0xf, true);  // row_ror:4
  v = fmaxf(v, __int_as_float(t));
  t = __builtin_amdgcn_update_dpp(0, __float_as_int(v), 0x128, 0xf, 0xf, true);  // row_ror:8
  v = fmaxf(v, __int_as_float(t));
  return v;
}

// merged split: x -> xh/xl, qkv_w -> qwh/qwl, out_w -> owh (hi only; out-proj
// error from bf16 W is ~0.003, negligible vs 0.105 threshold)
__global__ void split_all(const float* __restrict__ x, const float* __restrict__ qw,
                          const float* __restrict__ ow,
                          ushort* __restrict__ xh, ushort* __restrict__ xl,
                          ushort* __restrict__ qwh, ushort* __restrict__ qwl,
                          ushort* __restrict__ owh, int n1, int n2) {
  int i = blockIdx.x * blockDim.x + threadIdx.x;
  if (i < n1) {
    float v = x[i];
    ushort h = f2bf(v);
    xh[i] = h;
    xl[i] = f2bf(v - bf2f(h));
  } else if (i < n1 + n2) {
    int j = i - n1;
    float v = qw[j];
    ushort h = f2bf(v);
    qwh[j] = h;
    qwl[j] = f2bf(v - bf2f(h));
  } else {
    int j = i - n1 - n2;
    owh[j] = f2bf(ow[j]);
  }
}

// C[m,n] = sum_k A[m,k]*B[n,k] (both K-contiguous), global_load_lds staging.
// mode 0: 3-term split, C += bias -> Cout fp32.
// mode 1: QKV scatter; Q,K blocks 3-term; V blocks (bn>=12) 1-term (V only
//         needs bf16: ctx error ~0.003); V via LDS transpose.
// mode 2: 1-term plain bf16, C += bias -> Cout fp32 (out-proj: error ~0.003).
__global__ __launch_bounds__(256) void gemm_bt_split(
    const ushort* __restrict__ Ah, const ushort* __restrict__ Al,
    const ushort* __restrict__ Bh, const ushort* __restrict__ Bl,
    int M, int N, int K, int mode,
    float* __restrict__ Cout, const float* __restrict__ bias,
    ushort* __restrict__ Qh, ushort* __restrict__ Ql,
    ushort* __restrict__ Kh, ushort* __restrict__ Kl,
    ushort* __restrict__ Vt) {
  __shared__ ushort smem[4 * 128 * 32];
  ushort* sAh = smem;
  ushort* sAl = smem + 4096;
  ushort* sBh = smem + 8192;
  ushort* sBl = smem + 12288;

  const int tid = threadIdx.x;
  const int lane = tid & 63;
  const int w = tid >> 6;
  const int wm = w >> 1, wn = w & 1;
  const int col = lane & 15, quad = lane >> 4;
  const int bm = blockIdx.x, bn = blockIdx.y;

  const bool oneterm = (mode == 2) || (mode == 1 && bn >= 12);
  const bool skipdma = (mode == 2) && (w == 1 || w == 3);  // no lo arrays

  const ushort* gsrc = (w == 0)   ? Ah + (size_t)bm * 128 * K
                       : (w == 1) ? Al + (size_t)bm * 128 * K
                       : (w == 2) ? Bh + (size_t)bn * 128 * K
                                  : Bl + (size_t)bn * 128 * K;
  ushort* lbase = (w == 0) ? sAh : (w == 1) ? sAl : (w == 2) ? sBh : sBl;
  const ushort* g0 = gsrc + (size_t)(lane >> 2) * K + (lane & 3) * 8;

  f32x4 acc[4][4];
  const f32x4 zz = {0.f, 0.f, 0.f, 0.f};
#pragma unroll
  for (int i = 0; i < 4; ++i)
#pragma unroll
    for (int j = 0; j < 4; ++j) acc[i][j] = zz;

  for (int kt = 0; kt < K; kt += 32) {
    __syncthreads();
    if (!skipdma) {
#pragma unroll
      for (int i = 0; i < 8; ++i) {
        __builtin_amdgcn_global_load_lds(
            (const GLOBAL_AS unsigned int*)(g0 + (size_t)i * 16 * K + kt),
            (LDS_AS unsigned int*)(lbase + i * 512), 16, 0, 0);
      }
    }
    asm volatile("s_waitcnt vmcnt(0)" ::: "memory");
    __syncthreads();

    if (oneterm) {
      short8 fah[4], fbh[4];
#pragma unroll
      for (int t = 0; t < 4; ++t) {
        fah[t] = *(const short8*)(&sAh[(wm * 64 + t * 16 + col) * 32 + quad * 8]);
        fbh[t] = *(const short8*)(&sBh[(wn * 64 + t * 16 + col) * 32 + quad * 8]);
      }
#pragma unroll
      for (int tm = 0; tm < 4; ++tm)
#pragma unroll
        for (int tn = 0; tn < 4; ++tn)
          acc[tm][tn] = __builtin_amdgcn_mfma_f32_16x16x32_bf16(fah[tm], fbh[tn], acc[tm][tn], 0, 0, 0);
    } else {
      short8 fah[4], fal[4], fbh[4], fbl[4];
#pragma unroll
      for (int t = 0; t < 4; ++t) {
        int ra = (wm * 64 + t * 16 + col) * 32 + quad * 8;
        fah[t] = *(const short8*)(&sAh[ra]);
        fal[t] = *(const short8*)(&sAl[ra]);
        int rb = (wn * 64 + t * 16 + col) * 32 + quad * 8;
        fbh[t] = *(const short8*)(&sBh[rb]);
        fbl[t] = *(const short8*)(&sBl[rb]);
      }
#pragma unroll
      for (int tm = 0; tm < 4; ++tm)
#pragma unroll
        for (int tn = 0; tn < 4; ++tn) {
          acc[tm][tn] = __builtin_amdgcn_mfma_f32_16x16x32_bf16(fah[tm], fbh[tn], acc[tm][tn], 0, 0, 0);
          acc[tm][tn] = __builtin_amdgcn_mfma_f32_16x16x32_bf16(fah[tm], fbl[tn], acc[tm][tn], 0, 0, 0);
          acc[tm][tn] = __builtin_amdgcn_mfma_f32_16x16x32_bf16(fal[tm], fbh[tn], acc[tm][tn], 0, 0, 0);
        }
    }
  }

  const int m_base = bm * 128 + wm * 64;
  const int n_base = bn * 128 + wn * 64;

  if (mode != 1) {
#pragma unroll
    for (int tm = 0; tm < 4; ++tm)
#pragma unroll
      for (int tn = 0; tn < 4; ++tn) {
        int gn = n_base + tn * 16 + col;
        float b = bias[gn];
#pragma unroll
        for (int rr = 0; rr < 4; ++rr) {
          int gm = m_base + tm * 16 + quad * 4 + rr;
          Cout[(size_t)gm * N + gn] = acc[tm][tn][rr] + b;
        }
      }
  } else {
    int reg = bn / 6;  // 0:Q 1:K 2:V (uniform per block)
    if (reg < 2) {
#pragma unroll
      for (int tm = 0; tm < 4; ++tm)
#pragma unroll
        for (int tn = 0; tn < 4; ++tn) {
          int el = (bn % 6) * 128 + wn * 64 + tn * 16 + col;  // 0..767
          int hh = el >> 6, dd = el & 63;
#pragma unroll
          for (int rr = 0; rr < 4; ++rr) {
            int gm = m_base + tm * 16 + quad * 4 + rr;
            float v = acc[tm][tn][rr];
            if (reg == 0) {
              v *= QSCALE;
              ushort hi = f2bf(v);
              size_t idx = ((size_t)hh * SEQ + gm) * HD + dd;  // Q unswizzled
              Qh[idx] = hi;
              Ql[idx] = f2bf(v - bf2f(hi));
            } else {
              // K swizzled: chunk' = chunk ^ (key&7) for attn's DMA image
              ushort hi = f2bf(v);
              int pc = ((dd >> 3) ^ (gm & 7)) & 7;
              size_t idx = ((size_t)hh * SEQ + gm) * HD + pc * 8 + (dd & 7);
              Kh[idx] = hi;
              Kl[idx] = f2bf(v - bf2f(hi));
            }
          }
        }
    } else {
      // ---- V: LDS transpose -> coalesced swizzled stores ----
      __syncthreads();
      ushort* vt_tile = smem;  // 128*128 ushort = 32KB
#pragma unroll
      for (int tm = 0; tm < 4; ++tm)
#pragma unroll
        for (int tn = 0; tn < 4; ++tn) {
          int el = wn * 64 + tn * 16 + col;
#pragma unroll
          for (int rr = 0; rr < 4; ++rr) {
            int seq = wm * 64 + tm * 16 + quad * 4 + rr;
            int cc = (((seq >> 3) & 7) ^ (el & 7)) & 7;
            vt_tile[el * 128 + (seq & 64) + cc * 8 + (seq & 7)] = f2bf(acc[tm][tn][rr]);
          }
        }
      __syncthreads();
      int el = tid >> 1;
      int elg = (bn % 6) * 128 + el;
      int hh = elg >> 6, dd = elg & 63;
      ushort* grow = Vt + (size_t)(hh * HD + dd) * SEQ + bm * 128;
#pragma unroll
      for (int i = 0; i < 8; ++i) {
        int c = ((tid & 1) * 8 + i + el) & 15;
        *(uint4*)(grow + c * 8) = *(const uint4*)(&vt_tile[el * 128 + c * 8]);
      }
    }
  }
}

// Flash attention R9: R8 structure (64 q-rows/block, 64-key double-buffered
// DMA tiles, 3 blocks/CU, DPP max, MFMA rowsum). Writes Ch ONLY (ctx lo-part
// dropped: out-proj bf16 error ~0.003 << threshold) — halves epilogue writes
// and removes 16 pack insts/iter... (epilogue only).
__global__ __launch_bounds__(256, 3) void attn_k(
    const ushort* __restrict__ Qh, const ushort* __restrict__ Ql,
    const ushort* __restrict__ Kh, const ushort* __restrict__ Kl,
    const ushort* __restrict__ Vt, ushort* __restrict__ Ch) {
  __shared__ ushort sKh[2][64 * 64];  // [key][chunk^key&7][8]
  __shared__ ushort sKl[2][64 * 64];
  __shared__ ushort sVt[2][64 * 64];  // [dim][chunk^dim&7][8]
  __shared__ ushort sP[4][16 * 32];   // per-wave 32-key half

  const int tid = threadIdx.x, lane = tid & 63, w = tid >> 6;
  const int col = lane & 15, quad = lane >> 4;
  const int h = blockIdx.y;
  const int q0 = blockIdx.x * 64 + w * 16;

  const ushort* qh_base = Qh + ((size_t)h * SEQ + q0 + col) * HD;
  const ushort* ql_base = Ql + ((size_t)h * SEQ + q0 + col) * HD;
  short8 fqh[2], fql[2];
#pragma unroll
  for (int ks = 0; ks < 2; ++ks) {
    fqh[ks] = *(const short8*)(qh_base + ks * 32 + quad * 8);
    fql[ks] = *(const short8*)(ql_base + ks * 32 + quad * 8);
  }

  const short ONE = (short)0x3F80;
  const short8 ones = {ONE, ONE, ONE, ONE, ONE, ONE, ONE, ONE};

  float m2[4], ell[4];
  f32x4 o[4];
  const f32x4 zz = {0.f, 0.f, 0.f, 0.f};
#pragma unroll
  for (int i = 0; i < 4; ++i) { m2[i] = -1e30f; ell[i] = 0.f; o[i] = zz; }

  const ushort* khg = Kh + (size_t)h * SEQ * HD;  // swizzled [key][64]
  const ushort* klg = Kl + (size_t)h * SEQ * HD;
  const ushort* vtg = Vt + (size_t)h * HD * SEQ;  // swizzled [dim][SEQ]
  ushort* pw = &sP[w][0];

  // staging pointers: wave w owns chunks idx = w*6 .. w*6+5; advance per iter
  const ushort* gp[6];
  ushort* lp[6];
  int gstep[6];
#pragma unroll
  for (int i = 0; i < 6; ++i) {
    int idx = w * 6 + i;
    int arr = idx >> 3, j = idx & 7;
    if (arr == 0) {
      gp[i] = khg + (size_t)(j * 8 + (lane >> 3)) * 64 + (lane & 7) * 8;
      lp[i] = &sKh[0][j * 512];
      gstep[i] = 64 * 64;
    } else if (arr == 1) {
      gp[i] = klg + (size_t)(j * 8 + (lane >> 3)) * 64 + (lane & 7) * 8;
      lp[i] = &sKl[0][j * 512];
      gstep[i] = 64 * 64;
    } else {
      gp[i] = vtg + (size_t)(j * 8 + (lane >> 3)) * SEQ + (lane & 7) * 8;
      lp[i] = &sVt[0][j * 512];
      gstep[i] = 64;
    }
  }

  // initial stage into buf 0
#pragma unroll
  for (int i = 0; i < 6; ++i) {
    __builtin_amdgcn_global_load_lds((const GLOBAL_AS unsigned int*)gp[i],
                                     (LDS_AS unsigned int*)lp[i], 16, 0, 0);
    gp[i] += gstep[i];
  }

  // loop-invariant LDS byte offsets
  const int koff0 = (col * 64 + ((quad ^ (col & 7)) & 7) * 8) * 2;        // ks=0
  const int koff1 = (col * 64 + (((4 + quad) ^ (col & 7)) & 7) * 8) * 2;  // ks=1
  const int fpoff = (col * 32 + ((quad ^ (col & 3) ^ ((col >> 2) & 3)) & 3) * 8) * 2;
  const int voff0 = koff0;
  const int voff1 = koff1;

  auto do_iter = [&](int buf) {
    asm volatile("s_waitcnt vmcnt(0)" ::: "memory");
    __syncthreads();
#pragma unroll
    for (int i = 0; i < 6; ++i) {
      __builtin_amdgcn_global_load_lds(
          (const GLOBAL_AS unsigned int*)gp[i],
          (LDS_AS unsigned int*)(lp[i] + (buf ^ 1) * 4096), 16, 0, 0);
      gp[i] += gstep[i];
    }
    const char* kh = (const char*)&sKh[buf][0];
    const char* kl = (const char*)&sKl[buf][0];
    const char* vt = (const char*)&sVt[buf][0];

    f32x4 s[4];
#pragma unroll
    for (int tn = 0; tn < 4; ++tn) {
      f32x4 a = zz;
      short8 kh0 = *(const short8*)(kh + tn * 2048 + koff0);
      short8 kl0 = *(const short8*)(kl + tn * 2048 + koff0);
      short8 kh1 = *(const short8*)(kh + tn * 2048 + koff1);
      short8 kl1 = *(const short8*)(kl + tn * 2048 + koff1);
      a = __builtin_amdgcn_mfma_f32_16x16x32_bf16(fqh[0], kh0, a, 0, 0, 0);
      a = __builtin_amdgcn_mfma_f32_16x16x32_bf16(fqh[0], kl0, a, 0, 0, 0);
      a = __builtin_amdgcn_mfma_f32_16x16x32_bf16(fql[0], kh0, a, 0, 0, 0);
      a = __builtin_amdgcn_mfma_f32_16x16x32_bf16(fqh[1], kh1, a, 0, 0, 0);
      a = __builtin_amdgcn_mfma_f32_16x16x32_bf16(fqh[1], kl1, a, 0, 0, 0);
      a = __builtin_amdgcn_mfma_f32_16x16x32_bf16(fql[1], kh1, a, 0, 0, 0);
      s[tn] = a;
    }

    float mn[4], alpha[4];
#pragma unroll
    for (int rr = 0; rr < 4; ++rr) {
      float vm = fmaxf(fmaxf(s[0][rr], s[1][rr]), fmaxf(s[2][rr], s[3][rr]));
      vm = dpp_max16(vm);
      mn[rr] = fmaxf(m2[rr], vm);
      alpha[rr] = exp2f(m2[rr] - mn[rr]);
      m2[rr] = mn[rr];
      ell[rr] *= alpha[rr];
    }
#pragma unroll
    for (int td = 0; td < 4; ++td)
#pragma unroll
      for (int rr = 0; rr < 4; ++rr) o[td][rr] *= alpha[rr];

    f32x4 psum = zz;
#pragma unroll
    for (int hh = 0; hh < 2; ++hh) {
#pragma unroll
      for (int t2 = 0; t2 < 2; ++t2) {
        int tn = hh * 2 + t2;
#pragma unroll
        for (int rr = 0; rr < 4; ++rr) {
          float p = exp2f(s[tn][rr] - mn[rr]);
          int row = quad * 4 + rr;
          int cc = t2 * 16 + col;
          int slot = ((cc >> 3) ^ rr ^ quad) & 3;
          pw[row * 32 + slot * 8 + (cc & 7)] =
              (ushort)(__float_as_uint(p) >> 16);  // trunc: ell uses stored P
        }
      }
      asm volatile("s_waitcnt lgkmcnt(0)" ::: "memory");
      short8 fp = *(const short8*)((const char*)pw + fpoff);
      psum = __builtin_amdgcn_mfma_f32_16x16x32_bf16(fp, ones, psum, 0, 0, 0);
      const int vo = hh ? voff1 : voff0;
#pragma unroll
      for (int td = 0; td < 4; ++td) {
        short8 fv = *(const short8*)(vt + td * 2048 + vo);
        o[td] = __builtin_amdgcn_mfma_f32_16x16x32_bf16(fp, fv, o[td], 0, 0, 0);
      }
    }
#pragma unroll
    for (int rr = 0; rr < 4; ++rr) ell[rr] += psum[rr];
  };

  for (int kb = 0; kb < SEQ; kb += 128) {
    do_iter(0);
    do_iter(1);
  }

  // epilogue: normalize, bf16 ctx [4096][768] (hi only)
#pragma unroll
  for (int td = 0; td < 4; ++td)
#pragma unroll
    for (int rr = 0; rr < 4; ++rr) {
      float v = o[td][rr] / ell[rr];
      int l = q0 + quad * 4 + rr;
      int d = h * 64 + td * 16 + col;
      Ch[(size_t)l * EMB + d] = f2bf(v);
    }
}

extern "C" void kernel_launch(void* const* d_in, const int* in_sizes, int n_in,
                              void* d_out, int out_size, void* d_ws, size_t ws_size,
                              hipStream_t stream) {
  const float* x = (const float*)d_in[0];       // [4096][768]
  const float* qkv_w = (const float*)d_in[1];   // [2304][768]
  const float* out_w = (const float*)d_in[2];   // [768][768]
  const float* out_b = (const float*)d_in[3];   // [768]
  float* out = (float*)d_out;                   // [4096][768]

  char* p = (char*)d_ws;
  auto carve = [&](size_t bytes) {
    char* q = p;
    p += (bytes + 255) & ~(size_t)255;
    return q;
  };
  const size_t NX = (size_t)SEQ * EMB;       // 3,145,728
  const size_t NQW = (size_t)3 * EMB * EMB;  // 1,769,472
  const size_t NOW = (size_t)EMB * EMB;      // 589,824
  const size_t NQKV = (size_t)NH * SEQ * HD; // 3,145,728

  ushort* xh = (ushort*)carve(NX * 2);
  ushort* xl = (ushort*)carve(NX * 2);
  ushort* qwh = (ushort*)carve(NQW * 2);
  ushort* qwl = (ushort*)carve(NQW * 2);
  ushort* owh = (ushort*)carve(NOW * 2);
  ushort* Qh = (ushort*)carve(NQKV * 2);
  ushort* Ql = (ushort*)carve(NQKV * 2);
  ushort* Kh = (ushort*)carve(NQKV * 2);
  ushort* Kl = (ushort*)carve(NQKV * 2);
  ushort* Vt = (ushort*)carve(NQKV * 2);
  ushort* Ch = (ushort*)carve(NX * 2);

  const int ntot = (int)(NX + NQW + NOW);  // 5,505,024 = 21504 * 256
  split_all<<<dim3(ntot / 256), 256, 0, stream>>>(
      x, qkv_w, out_w, xh, xl, qwh, qwl, owh, (int)NX, (int)NQW);

  // QKV: M=4096, N=2304, K=768 -> scatter epilogue (K/V swizzled; V 1-term)
  gemm_bt_split<<<dim3(32, 18), 256, 0, stream>>>(
      xh, xl, qwh, qwl, SEQ, 3 * EMB, EMB, 1,
      nullptr, nullptr, Qh, Ql, Kh, Kl, Vt);

  attn_k<<<dim3(SEQ / 64, NH), 256, 0, stream>>>(Qh, Ql, Kh, Kl, Vt, Ch);

  // out proj: M=4096, N=768, K=768, 1-term bf16 + bias -> d_out
  gemm_bt_split<<<dim3(32, 6), 256, 0, stream>>>(
      Ch, Ch, owh, owh, SEQ, EMB, EMB, 2,
      out, out_b, nullptr, nullptr, nullptr, nullptr, nullptr);
}

// Round 10
// 297.849 us; speedup vs baseline: 1.4855x; 1.0799x over previous
//
#include <hip/hip_runtime.h>

typedef __attribute__((ext_vector_type(8))) short short8;
typedef __attribute__((ext_vector_type(4))) float f32x4;

#define EMB 768
#define SEQ 4096
#define NH 12
#define HD 64
// 8 * log2(e): folds the score scale AND the exp->exp2 conversion into Q
#define QSCALE 11.541560327111707f

#define GLOBAL_AS __attribute__((address_space(1)))
#define LDS_AS __attribute__((address_space(3)))

__device__ inline ushort f2bf(float v) {
  union { float f; unsigned int u; } x; x.f = v;
  unsigned int r = x.u + 0x7fffu + ((x.u >> 16) & 1u);
  return (ushort)(r >> 16);
}
__device__ inline float bf2f(ushort u) {
  union { float f; unsigned int u32; } x; x.u32 = ((unsigned int)u) << 16;
  return x.f;
}

// 16-lane max reduction on the VALU via DPP (no LDS pipe, no shuffle latency).
__device__ inline float dpp_max16(float v) {
  int t;
  t = __builtin_amdgcn_update_dpp(0, __float_as_int(v), 0xB1, 0xf, 0xf, true);   // quad_perm(1,0,3,2)
  v = fmaxf(v, __int_as_float(t));
  t = __builtin_amdgcn_update_dpp(0, __float_as_int(v), 0x4E, 0xf, 0xf, true);   // quad_perm(2,3,0,1)
  v = fmaxf(v, __int_as_float(t));
  t = __builtin_amdgcn_update_dpp(0, __float_as_int(v), 0x124, 0xf, 0xf, true);  // row_ror:4
  v = fmaxf(v, __int_as_float(t));
  t = __builtin_amdgcn_update_dpp(0, __float_as_int(v), 0x128, 0xf, 0xf, true);  // row_ror:8
  v = fmaxf(v, __int_as_float(t));
  return v;
}

// merged split: x -> xh/xl, qkv_w -> qwh/qwl, out_w -> owh (hi only)
__global__ void split_all(const float* __restrict__ x, const float* __restrict__ qw,
                          const float* __restrict__ ow,
                          ushort* __restrict__ xh, ushort* __restrict__ xl,
                          ushort* __restrict__ qwh, ushort* __restrict__ qwl,
                          ushort* __restrict__ owh, int n1, int n2) {
  int i = blockIdx.x * blockDim.x + threadIdx.x;
  if (i < n1) {
    float v = x[i];
    ushort h = f2bf(v);
    xh[i] = h;
    xl[i] = f2bf(v - bf2f(h));
  } else if (i < n1 + n2) {
    int j = i - n1;
    float v = qw[j];
    ushort h = f2bf(v);
    qwh[j] = h;
    qwl[j] = f2bf(v - bf2f(h));
  } else {
    int j = i - n1 - n2;
    owh[j] = f2bf(ow[j]);
  }
}

// C[m,n] = sum_k A[m,k]*B[n,k] (both K-contiguous), global_load_lds staging,
// R10: DOUBLE-BUFFERED K-loop (R8 attn pattern: wait at iter top covers DMAs
// issued a full iteration earlier -> per-iter drain ~0; R9 had a full
// vmcnt(0)+barrier drain every BK=32 = ~30-40% stall, MfmaUtil ~19%).
// mode 1: QKV scatter; Q,K blocks 3-term; V blocks (bn>=12) 1-term.
// mode 2: 1-term plain bf16, C += bias -> Cout fp32 (out-proj).
__global__ __launch_bounds__(256, 2) void gemm_bt_split(
    const ushort* __restrict__ Ah, const ushort* __restrict__ Al,
    const ushort* __restrict__ Bh, const ushort* __restrict__ Bl,
    int M, int N, int K, int mode,
    float* __restrict__ Cout, const float* __restrict__ bias,
    ushort* __restrict__ Qh, ushort* __restrict__ Ql,
    ushort* __restrict__ Kh, ushort* __restrict__ Kl,
    ushort* __restrict__ Vt) {
  __shared__ ushort smem[2][4 * 128 * 32];  // 2 x 32KB staging buffers

  const int tid = threadIdx.x;
  const int lane = tid & 63;
  const int w = tid >> 6;
  const int wm = w >> 1, wn = w & 1;
  const int col = lane & 15, quad = lane >> 4;
  const int bm = blockIdx.x, bn = blockIdx.y;

  const bool oneterm = (mode == 2) || (mode == 1 && bn >= 12);
  const bool skipdma = oneterm && (w == 1 || w == 3);  // lo tiles unused

  const ushort* gsrc = (w == 0)   ? Ah + (size_t)bm * 128 * K
                       : (w == 1) ? Al + (size_t)bm * 128 * K
                       : (w == 2) ? Bh + (size_t)bn * 128 * K
                                  : Bl + (size_t)bn * 128 * K;
  const int loff = w * 4096;  // matrix offset inside a buffer
  const ushort* g0 = gsrc + (size_t)(lane >> 2) * K + (lane & 3) * 8;

  f32x4 acc[4][4];
  const f32x4 zz = {0.f, 0.f, 0.f, 0.f};
#pragma unroll
  for (int i = 0; i < 4; ++i)
#pragma unroll
    for (int j = 0; j < 4; ++j) acc[i][j] = zz;

#define GSTAGE(b, kt)                                                       \
  if (!skipdma) {                                                           \
    _Pragma("unroll") for (int i = 0; i < 8; ++i) {                         \
      __builtin_amdgcn_global_load_lds(                                     \
          (const GLOBAL_AS unsigned int*)(g0 + (size_t)i * 16 * K + (kt)),  \
          (LDS_AS unsigned int*)(&smem[b][loff + i * 512]), 16, 0, 0);      \
    }                                                                       \
  }

  GSTAGE(0, 0);
  const int nk = K / 32;
  for (int it = 0; it < nk; ++it) {
    const int buf = it & 1;
    // current tile's DMAs (issued one iteration ago) done; barrier also
    // guarantees all waves finished reading buf^1 -> safe to overwrite
    asm volatile("s_waitcnt vmcnt(0)" ::: "memory");
    __syncthreads();
    if (it + 1 < nk) GSTAGE(buf ^ 1, (it + 1) * 32);

    const ushort* sAh = &smem[buf][0];
    const ushort* sAl = &smem[buf][4096];
    const ushort* sBh = &smem[buf][8192];
    const ushort* sBl = &smem[buf][12288];

    if (oneterm) {
      short8 fah[4], fbh[4];
#pragma unroll
      for (int t = 0; t < 4; ++t) {
        fah[t] = *(const short8*)(&sAh[(wm * 64 + t * 16 + col) * 32 + quad * 8]);
        fbh[t] = *(const short8*)(&sBh[(wn * 64 + t * 16 + col) * 32 + quad * 8]);
      }
#pragma unroll
      for (int tm = 0; tm < 4; ++tm)
#pragma unroll
        for (int tn = 0; tn < 4; ++tn)
          acc[tm][tn] = __builtin_amdgcn_mfma_f32_16x16x32_bf16(fah[tm], fbh[tn], acc[tm][tn], 0, 0, 0);
    } else {
      short8 fah[4], fal[4], fbh[4], fbl[4];
#pragma unroll
      for (int t = 0; t < 4; ++t) {
        int ra = (wm * 64 + t * 16 + col) * 32 + quad * 8;
        fah[t] = *(const short8*)(&sAh[ra]);
        fal[t] = *(const short8*)(&sAl[ra]);
        int rb = (wn * 64 + t * 16 + col) * 32 + quad * 8;
        fbh[t] = *(const short8*)(&sBh[rb]);
        fbl[t] = *(const short8*)(&sBl[rb]);
      }
#pragma unroll
      for (int tm = 0; tm < 4; ++tm)
#pragma unroll
        for (int tn = 0; tn < 4; ++tn) {
          acc[tm][tn] = __builtin_amdgcn_mfma_f32_16x16x32_bf16(fah[tm], fbh[tn], acc[tm][tn], 0, 0, 0);
          acc[tm][tn] = __builtin_amdgcn_mfma_f32_16x16x32_bf16(fah[tm], fbl[tn], acc[tm][tn], 0, 0, 0);
          acc[tm][tn] = __builtin_amdgcn_mfma_f32_16x16x32_bf16(fal[tm], fbh[tn], acc[tm][tn], 0, 0, 0);
        }
    }
  }

  const int m_base = bm * 128 + wm * 64;
  const int n_base = bn * 128 + wn * 64;

  if (mode != 1) {
#pragma unroll
    for (int tm = 0; tm < 4; ++tm)
#pragma unroll
      for (int tn = 0; tn < 4; ++tn) {
        int gn = n_base + tn * 16 + col;
        float b = bias[gn];
#pragma unroll
        for (int rr = 0; rr < 4; ++rr) {
          int gm = m_base + tm * 16 + quad * 4 + rr;
          Cout[(size_t)gm * N + gn] = acc[tm][tn][rr] + b;
        }
      }
  } else {
    int reg = bn / 6;  // 0:Q 1:K 2:V (uniform per block)
    if (reg < 2) {
#pragma unroll
      for (int tm = 0; tm < 4; ++tm)
#pragma unroll
        for (int tn = 0; tn < 4; ++tn) {
          int el = (bn % 6) * 128 + wn * 64 + tn * 16 + col;  // 0..767
          int hh = el >> 6, dd = el & 63;
#pragma unroll
          for (int rr = 0; rr < 4; ++rr) {
            int gm = m_base + tm * 16 + quad * 4 + rr;
            float v = acc[tm][tn][rr];
            if (reg == 0) {
              v *= QSCALE;
              ushort hi = f2bf(v);
              size_t idx = ((size_t)hh * SEQ + gm) * HD + dd;  // Q unswizzled
              Qh[idx] = hi;
              Ql[idx] = f2bf(v - bf2f(hi));
            } else {
              // K swizzled: chunk' = chunk ^ (key&7) for attn's DMA image
              ushort hi = f2bf(v);
              int pc = ((dd >> 3) ^ (gm & 7)) & 7;
              size_t idx = ((size_t)hh * SEQ + gm) * HD + pc * 8 + (dd & 7);
              Kh[idx] = hi;
              Kl[idx] = f2bf(v - bf2f(hi));
            }
          }
        }
    } else {
      // ---- V: LDS transpose -> coalesced swizzled stores ----
      __syncthreads();
      ushort* vt_tile = &smem[0][0];  // 128*128 ushort = 32KB
#pragma unroll
      for (int tm = 0; tm < 4; ++tm)
#pragma unroll
        for (int tn = 0; tn < 4; ++tn) {
          int el = wn * 64 + tn * 16 + col;
#pragma unroll
          for (int rr = 0; rr < 4; ++rr) {
            int seq = wm * 64 + tm * 16 + quad * 4 + rr;
            int cc = (((seq >> 3) & 7) ^ (el & 7)) & 7;
            vt_tile[el * 128 + (seq & 64) + cc * 8 + (seq & 7)] = f2bf(acc[tm][tn][rr]);
          }
        }
      __syncthreads();
      int el = tid >> 1;
      int elg = (bn % 6) * 128 + el;
      int hh = elg >> 6, dd = elg & 63;
      ushort* grow = Vt + (size_t)(hh * HD + dd) * SEQ + bm * 128;
#pragma unroll
      for (int i = 0; i < 8; ++i) {
        int c = ((tid & 1) * 8 + i + el) & 15;
        *(uint4*)(grow + c * 8) = *(const uint4*)(&vt_tile[el * 128 + c * 8]);
      }
    }
  }
}

// Flash attention (unchanged from R9): 64 q-rows/block, 64-key double-buffered
// DMA tiles, 3 blocks/CU, DPP max, MFMA rowsum, Ch-only epilogue.
__global__ __launch_bounds__(256, 3) void attn_k(
    const ushort* __restrict__ Qh, const ushort* __restrict__ Ql,
    const ushort* __restrict__ Kh, const ushort* __restrict__ Kl,
    const ushort* __restrict__ Vt, ushort* __restrict__ Ch) {
  __shared__ ushort sKh[2][64 * 64];  // [key][chunk^key&7][8]
  __shared__ ushort sKl[2][64 * 64];
  __shared__ ushort sVt[2][64 * 64];  // [dim][chunk^dim&7][8]
  __shared__ ushort sP[4][16 * 32];   // per-wave 32-key half

  const int tid = threadIdx.x, lane = tid & 63, w = tid >> 6;
  const int col = lane & 15, quad = lane >> 4;
  const int h = blockIdx.y;
  const int q0 = blockIdx.x * 64 + w * 16;

  const ushort* qh_base = Qh + ((size_t)h * SEQ + q0 + col) * HD;
  const ushort* ql_base = Ql + ((size_t)h * SEQ + q0 + col) * HD;
  short8 fqh[2], fql[2];
#pragma unroll
  for (int ks = 0; ks < 2; ++ks) {
    fqh[ks] = *(const short8*)(qh_base + ks * 32 + quad * 8);
    fql[ks] = *(const short8*)(ql_base + ks * 32 + quad * 8);
  }

  const short ONE = (short)0x3F80;
  const short8 ones = {ONE, ONE, ONE, ONE, ONE, ONE, ONE, ONE};

  float m2[4], ell[4];
  f32x4 o[4];
  const f32x4 zz = {0.f, 0.f, 0.f, 0.f};
#pragma unroll
  for (int i = 0; i < 4; ++i) { m2[i] = -1e30f; ell[i] = 0.f; o[i] = zz; }

  const ushort* khg = Kh + (size_t)h * SEQ * HD;  // swizzled [key][64]
  const ushort* klg = Kl + (size_t)h * SEQ * HD;
  const ushort* vtg = Vt + (size_t)h * HD * SEQ;  // swizzled [dim][SEQ]
  ushort* pw = &sP[w][0];

  const ushort* gp[6];
  ushort* lp[6];
  int gstep[6];
#pragma unroll
  for (int i = 0; i < 6; ++i) {
    int idx = w * 6 + i;
    int arr = idx >> 3, j = idx & 7;
    if (arr == 0) {
      gp[i] = khg + (size_t)(j * 8 + (lane >> 3)) * 64 + (lane & 7) * 8;
      lp[i] = &sKh[0][j * 512];
      gstep[i] = 64 * 64;
    } else if (arr == 1) {
      gp[i] = klg + (size_t)(j * 8 + (lane >> 3)) * 64 + (lane & 7) * 8;
      lp[i] = &sKl[0][j * 512];
      gstep[i] = 64 * 64;
    } else {
      gp[i] = vtg + (size_t)(j * 8 + (lane >> 3)) * SEQ + (lane & 7) * 8;
      lp[i] = &sVt[0][j * 512];
      gstep[i] = 64;
    }
  }

#pragma unroll
  for (int i = 0; i < 6; ++i) {
    __builtin_amdgcn_global_load_lds((const GLOBAL_AS unsigned int*)gp[i],
                                     (LDS_AS unsigned int*)lp[i], 16, 0, 0);
    gp[i] += gstep[i];
  }

  const int koff0 = (col * 64 + ((quad ^ (col & 7)) & 7) * 8) * 2;        // ks=0
  const int koff1 = (col * 64 + (((4 + quad) ^ (col & 7)) & 7) * 8) * 2;  // ks=1
  const int fpoff = (col * 32 + ((quad ^ (col & 3) ^ ((col >> 2) & 3)) & 3) * 8) * 2;
  const int voff0 = koff0;
  const int voff1 = koff1;

  auto do_iter = [&](int buf) {
    asm volatile("s_waitcnt vmcnt(0)" ::: "memory");
    __syncthreads();
#pragma unroll
    for (int i = 0; i < 6; ++i) {
      __builtin_amdgcn_global_load_lds(
          (const GLOBAL_AS unsigned int*)gp[i],
          (LDS_AS unsigned int*)(lp[i] + (buf ^ 1) * 4096), 16, 0, 0);
      gp[i] += gstep[i];
    }
    const char* kh = (const char*)&sKh[buf][0];
    const char* kl = (const char*)&sKl[buf][0];
    const char* vt = (const char*)&sVt[buf][0];

    f32x4 s[4];
#pragma unroll
    for (int tn = 0; tn < 4; ++tn) {
      f32x4 a = zz;
      short8 kh0 = *(const short8*)(kh + tn * 2048 + koff0);
      short8 kl0 = *(const short8*)(kl + tn * 2048 + koff0);
      short8 kh1 = *(const short8*)(kh + tn * 2048 + koff1);
      short8 kl1 = *(const short8*)(kl + tn * 2048 + koff1);
      a = __builtin_amdgcn_mfma_f32_16x16x32_bf16(fqh[0], kh0, a, 0, 0, 0);
      a = __builtin_amdgcn_mfma_f32_16x16x32_bf16(fqh[0], kl0, a, 0, 0, 0);
      a = __builtin_amdgcn_mfma_f32_16x16x32_bf16(fql[0], kh0, a, 0, 0, 0);
      a = __builtin_amdgcn_mfma_f32_16x16x32_bf16(fqh[1], kh1, a, 0, 0, 0);
      a = __builtin_amdgcn_mfma_f32_16x16x32_bf16(fqh[1], kl1, a, 0, 0, 0);
      a = __builtin_amdgcn_mfma_f32_16x16x32_bf16(fql[1], kh1, a, 0, 0, 0);
      s[tn] = a;
    }

    float mn[4], alpha[4];
#pragma unroll
    for (int rr = 0; rr < 4; ++rr) {
      float vm = fmaxf(fmaxf(s[0][rr], s[1][rr]), fmaxf(s[2][rr], s[3][rr]));
      vm = dpp_max16(vm);
      mn[rr] = fmaxf(m2[rr], vm);
      alpha[rr] = exp2f(m2[rr] - mn[rr]);
      m2[rr] = mn[rr];
      ell[rr] *= alpha[rr];
    }
#pragma unroll
    for (int td = 0; td < 4; ++td)
#pragma unroll
      for (int rr = 0; rr < 4; ++rr) o[td][rr] *= alpha[rr];

    f32x4 psum = zz;
#pragma unroll
    for (int hh = 0; hh < 2; ++hh) {
#pragma unroll
      for (int t2 = 0; t2 < 2; ++t2) {
        int tn = hh * 2 + t2;
#pragma unroll
        for (int rr = 0; rr < 4; ++rr) {
          float p = exp2f(s[tn][rr] - mn[rr]);
          int row = quad * 4 + rr;
          int cc = t2 * 16 + col;
          int slot = ((cc >> 3) ^ rr ^ quad) & 3;
          pw[row * 32 + slot * 8 + (cc & 7)] =
              (ushort)(__float_as_uint(p) >> 16);  // trunc: ell uses stored P
        }
      }
      asm volatile("s_waitcnt lgkmcnt(0)" ::: "memory");
      short8 fp = *(const short8*)((const char*)pw + fpoff);
      psum = __builtin_amdgcn_mfma_f32_16x16x32_bf16(fp, ones, psum, 0, 0, 0);
      const int vo = hh ? voff1 : voff0;
#pragma unroll
      for (int td = 0; td < 4; ++td) {
        short8 fv = *(const short8*)(vt + td * 2048 + vo);
        o[td] = __builtin_amdgcn_mfma_f32_16x16x32_bf16(fp, fv, o[td], 0, 0, 0);
      }
    }
#pragma unroll
    for (int rr = 0; rr < 4; ++rr) ell[rr] += psum[rr];
  };

  for (int kb = 0; kb < SEQ; kb += 128) {
    do_iter(0);
    do_iter(1);
  }

#pragma unroll
  for (int td = 0; td < 4; ++td)
#pragma unroll
    for (int rr = 0; rr < 4; ++rr) {
      float v = o[td][rr] / ell[rr];
      int l = q0 + quad * 4 + rr;
      int d = h * 64 + td * 16 + col;
      Ch[(size_t)l * EMB + d] = f2bf(v);
    }
}

extern "C" void kernel_launch(void* const* d_in, const int* in_sizes, int n_in,
                              void* d_out, int out_size, void* d_ws, size_t ws_size,
                              hipStream_t stream) {
  const float* x = (const float*)d_in[0];       // [4096][768]
  const float* qkv_w = (const float*)d_in[1];   // [2304][768]
  const float* out_w = (const float*)d_in[2];   // [768][768]
  const float* out_b = (const float*)d_in[3];   // [768]
  float* out = (float*)d_out;                   // [4096][768]

  char* p = (char*)d_ws;
  auto carve = [&](size_t bytes) {
    char* q = p;
    p += (bytes + 255) & ~(size_t)255;
    return q;
  };
  const size_t NX = (size_t)SEQ * EMB;       // 3,145,728
  const size_t NQW = (size_t)3 * EMB * EMB;  // 1,769,472
  const size_t NOW = (size_t)EMB * EMB;      // 589,824
  const size_t NQKV = (size_t)NH * SEQ * HD; // 3,145,728

  ushort* xh = (ushort*)carve(NX * 2);
  ushort* xl = (ushort*)carve(NX * 2);
  ushort* qwh = (ushort*)carve(NQW * 2);
  ushort* qwl = (ushort*)carve(NQW * 2);
  ushort* owh = (ushort*)carve(NOW * 2);
  ushort* Qh = (ushort*)carve(NQKV * 2);
  ushort* Ql = (ushort*)carve(NQKV * 2);
  ushort* Kh = (ushort*)carve(NQKV * 2);
  ushort* Kl = (ushort*)carve(NQKV * 2);
  ushort* Vt = (ushort*)carve(NQKV * 2);
  ushort* Ch = (ushort*)carve(NX * 2);

  const int ntot = (int)(NX + NQW + NOW);  // 5,505,024 = 21504 * 256
  split_all<<<dim3(ntot / 256), 256, 0, stream>>>(
      x, qkv_w, out_w, xh, xl, qwh, qwl, owh, (int)NX, (int)NQW);

  // QKV: M=4096, N=2304, K=768 -> scatter epilogue (K/V swizzled; V 1-term)
  gemm_bt_split<<<dim3(32, 18), 256, 0, stream>>>(
      xh, xl, qwh, qwl, SEQ, 3 * EMB, EMB, 1,
      nullptr, nullptr, Qh, Ql, Kh, Kl, Vt);

  attn_k<<<dim3(SEQ / 64, NH), 256, 0, stream>>>(Qh, Ql, Kh, Kl, Vt, Ch);

  // out proj: M=4096, N=768, K=768, 1-term bf16 + bias -> d_out
  gemm_bt_split<<<dim3(32, 6), 256, 0, stream>>>(
      Ch, Ch, owh, owh, SEQ, EMB, EMB, 2,
      out, out_b, nullptr, nullptr, nullptr, nullptr, nullptr);
}

// Round 11
// 276.830 us; speedup vs baseline: 1.5983x; 1.0759x over previous
//
#include <hip/hip_runtime.h>

typedef __attribute__((ext_vector_type(8))) short short8;
typedef __attribute__((ext_vector_type(4))) float f32x4;

#define EMB 768
#define SEQ 4096
#define NH 12
#define HD 64
// 8 * log2(e): folds the score scale AND the exp->exp2 conversion into Q
#define QSCALE 11.541560327111707f

#define GLOBAL_AS __attribute__((address_space(1)))
#define LDS_AS __attribute__((address_space(3)))

__device__ inline ushort f2bf(float v) {
  union { float f; unsigned int u; } x; x.f = v;
  unsigned int r = x.u + 0x7fffu + ((x.u >> 16) & 1u);
  return (ushort)(r >> 16);
}
__device__ inline float bf2f(ushort u) {
  union { float f; unsigned int u32; } x; x.u32 = ((unsigned int)u) << 16;
  return x.f;
}

// 16-lane max reduction on the VALU via DPP (no LDS pipe, no shuffle latency).
__device__ inline float dpp_max16(float v) {
  int t;
  t = __builtin_amdgcn_update_dpp(0, __float_as_int(v), 0xB1, 0xf, 0xf, true);   // quad_perm(1,0,3,2)
  v = fmaxf(v, __int_as_float(t));
  t = __builtin_amdgcn_update_dpp(0, __float_as_int(v), 0x4E, 0xf, 0xf, true);   // quad_perm(2,3,0,1)
  v = fmaxf(v, __int_as_float(t));
  t = __builtin_amdgcn_update_dpp(0, __float_as_int(v), 0x124, 0xf, 0xf, true);  // row_ror:4
  v = fmaxf(v, __int_as_float(t));
  t = __builtin_amdgcn_update_dpp(0, __float_as_int(v), 0x128, 0xf, 0xf, true);  // row_ror:8
  v = fmaxf(v, __int_as_float(t));
  return v;
}

// merged split (float4-vectorized): x -> xh/xl, qkv_w -> qwh/qwl, out_w -> owh
__global__ void split_all(const float* __restrict__ x, const float* __restrict__ qw,
                          const float* __restrict__ ow,
                          ushort* __restrict__ xh, ushort* __restrict__ xl,
                          ushort* __restrict__ qwh, ushort* __restrict__ qwl,
                          ushort* __restrict__ owh, int n14, int n24) {
  int i = blockIdx.x * blockDim.x + threadIdx.x;
  const float4* src;
  ushort4 *dh, *dl;
  int j;
  if (i < n14) {
    src = (const float4*)x; dh = (ushort4*)xh; dl = (ushort4*)xl; j = i;
  } else if (i < n14 + n24) {
    src = (const float4*)qw; dh = (ushort4*)qwh; dl = (ushort4*)qwl; j = i - n14;
  } else {
    j = i - n14 - n24;
    float4 v = ((const float4*)ow)[j];
    ushort4 h = {f2bf(v.x), f2bf(v.y), f2bf(v.z), f2bf(v.w)};
    ((ushort4*)owh)[j] = h;
    return;
  }
  float4 v = src[j];
  ushort4 h = {f2bf(v.x), f2bf(v.y), f2bf(v.z), f2bf(v.w)};
  ushort4 l = {f2bf(v.x - bf2f(h.x)), f2bf(v.y - bf2f(h.y)),
               f2bf(v.z - bf2f(h.z)), f2bf(v.w - bf2f(h.w))};
  dh[j] = h;
  dl[j] = l;
}

// C[m,n] = sum_k A[m,k]*B[n,k] (both K-contiguous), global_load_lds staging,
// double-buffered K-loop. mode 1: QKV scatter; Q,K 3-term; V (bn>=12) 1-term.
// mode 2: 1-term plain bf16, C += bias -> Cout fp32 (out-proj).
__global__ __launch_bounds__(256, 2) void gemm_bt_split(
    const ushort* __restrict__ Ah, const ushort* __restrict__ Al,
    const ushort* __restrict__ Bh, const ushort* __restrict__ Bl,
    int M, int N, int K, int mode,
    float* __restrict__ Cout, const float* __restrict__ bias,
    ushort* __restrict__ Qh, ushort* __restrict__ Ql,
    ushort* __restrict__ Kh, ushort* __restrict__ Kl,
    ushort* __restrict__ Vt) {
  __shared__ ushort smem[2][4 * 128 * 32];  // 2 x 32KB staging buffers

  const int tid = threadIdx.x;
  const int lane = tid & 63;
  const int w = tid >> 6;
  const int wm = w >> 1, wn = w & 1;
  const int col = lane & 15, quad = lane >> 4;
  const int bm = blockIdx.x, bn = blockIdx.y;

  const bool oneterm = (mode == 2) || (mode == 1 && bn >= 12);
  const bool skipdma = oneterm && (w == 1 || w == 3);  // lo tiles unused

  const ushort* gsrc = (w == 0)   ? Ah + (size_t)bm * 128 * K
                       : (w == 1) ? Al + (size_t)bm * 128 * K
                       : (w == 2) ? Bh + (size_t)bn * 128 * K
                                  : Bl + (size_t)bn * 128 * K;
  const int loff = w * 4096;  // matrix offset inside a buffer
  const ushort* g0 = gsrc + (size_t)(lane >> 2) * K + (lane & 3) * 8;

  f32x4 acc[4][4];
  const f32x4 zz = {0.f, 0.f, 0.f, 0.f};
#pragma unroll
  for (int i = 0; i < 4; ++i)
#pragma unroll
    for (int j = 0; j < 4; ++j) acc[i][j] = zz;

#define GSTAGE(b, kt)                                                       \
  if (!skipdma) {                                                           \
    _Pragma("unroll") for (int i = 0; i < 8; ++i) {                         \
      __builtin_amdgcn_global_load_lds(                                     \
          (const GLOBAL_AS unsigned int*)(g0 + (size_t)i * 16 * K + (kt)),  \
          (LDS_AS unsigned int*)(&smem[b][loff + i * 512]), 16, 0, 0);      \
    }                                                                       \
  }

  GSTAGE(0, 0);
  const int nk = K / 32;
  for (int it = 0; it < nk; ++it) {
    const int buf = it & 1;
    asm volatile("s_waitcnt vmcnt(0)" ::: "memory");
    __syncthreads();
    if (it + 1 < nk) GSTAGE(buf ^ 1, (it + 1) * 32);

    const ushort* sAh = &smem[buf][0];
    const ushort* sAl = &smem[buf][4096];
    const ushort* sBh = &smem[buf][8192];
    const ushort* sBl = &smem[buf][12288];

    if (oneterm) {
      short8 fah[4], fbh[4];
#pragma unroll
      for (int t = 0; t < 4; ++t) {
        fah[t] = *(const short8*)(&sAh[(wm * 64 + t * 16 + col) * 32 + quad * 8]);
        fbh[t] = *(const short8*)(&sBh[(wn * 64 + t * 16 + col) * 32 + quad * 8]);
      }
#pragma unroll
      for (int tm = 0; tm < 4; ++tm)
#pragma unroll
        for (int tn = 0; tn < 4; ++tn)
          acc[tm][tn] = __builtin_amdgcn_mfma_f32_16x16x32_bf16(fah[tm], fbh[tn], acc[tm][tn], 0, 0, 0);
    } else {
      short8 fah[4], fal[4], fbh[4], fbl[4];
#pragma unroll
      for (int t = 0; t < 4; ++t) {
        int ra = (wm * 64 + t * 16 + col) * 32 + quad * 8;
        fah[t] = *(const short8*)(&sAh[ra]);
        fal[t] = *(const short8*)(&sAl[ra]);
        int rb = (wn * 64 + t * 16 + col) * 32 + quad * 8;
        fbh[t] = *(const short8*)(&sBh[rb]);
        fbl[t] = *(const short8*)(&sBl[rb]);
      }
#pragma unroll
      for (int tm = 0; tm < 4; ++tm)
#pragma unroll
        for (int tn = 0; tn < 4; ++tn) {
          acc[tm][tn] = __builtin_amdgcn_mfma_f32_16x16x32_bf16(fah[tm], fbh[tn], acc[tm][tn], 0, 0, 0);
          acc[tm][tn] = __builtin_amdgcn_mfma_f32_16x16x32_bf16(fah[tm], fbl[tn], acc[tm][tn], 0, 0, 0);
          acc[tm][tn] = __builtin_amdgcn_mfma_f32_16x16x32_bf16(fal[tm], fbh[tn], acc[tm][tn], 0, 0, 0);
        }
    }
  }

  const int m_base = bm * 128 + wm * 64;
  const int n_base = bn * 128 + wn * 64;

  if (mode != 1) {
#pragma unroll
    for (int tm = 0; tm < 4; ++tm)
#pragma unroll
      for (int tn = 0; tn < 4; ++tn) {
        int gn = n_base + tn * 16 + col;
        float b = bias[gn];
#pragma unroll
        for (int rr = 0; rr < 4; ++rr) {
          int gm = m_base + tm * 16 + quad * 4 + rr;
          Cout[(size_t)gm * N + gn] = acc[tm][tn][rr] + b;
        }
      }
  } else {
    int reg = bn / 6;  // 0:Q 1:K 2:V (uniform per block)
    if (reg < 2) {
#pragma unroll
      for (int tm = 0; tm < 4; ++tm)
#pragma unroll
        for (int tn = 0; tn < 4; ++tn) {
          int el = (bn % 6) * 128 + wn * 64 + tn * 16 + col;  // 0..767
          int hh = el >> 6, dd = el & 63;
#pragma unroll
          for (int rr = 0; rr < 4; ++rr) {
            int gm = m_base + tm * 16 + quad * 4 + rr;
            float v = acc[tm][tn][rr];
            if (reg == 0) {
              v *= QSCALE;
              ushort hi = f2bf(v);
              size_t idx = ((size_t)hh * SEQ + gm) * HD + dd;  // Q unswizzled
              Qh[idx] = hi;
              Ql[idx] = f2bf(v - bf2f(hi));
            } else {
              // K swizzled: chunk' = chunk ^ (key&7) for attn's DMA image
              ushort hi = f2bf(v);
              int pc = ((dd >> 3) ^ (gm & 7)) & 7;
              size_t idx = ((size_t)hh * SEQ + gm) * HD + pc * 8 + (dd & 7);
              Kh[idx] = hi;
              Kl[idx] = f2bf(v - bf2f(hi));
            }
          }
        }
    } else {
      // ---- V: LDS transpose -> coalesced swizzled stores ----
      __syncthreads();
      ushort* vt_tile = &smem[0][0];  // 128*128 ushort = 32KB
#pragma unroll
      for (int tm = 0; tm < 4; ++tm)
#pragma unroll
        for (int tn = 0; tn < 4; ++tn) {
          int el = wn * 64 + tn * 16 + col;
#pragma unroll
          for (int rr = 0; rr < 4; ++rr) {
            int seq = wm * 64 + tm * 16 + quad * 4 + rr;
            int cc = (((seq >> 3) & 7) ^ (el & 7)) & 7;
            vt_tile[el * 128 + (seq & 64) + cc * 8 + (seq & 7)] = f2bf(acc[tm][tn][rr]);
          }
        }
      __syncthreads();
      int el = tid >> 1;
      int elg = (bn % 6) * 128 + el;
      int hh = elg >> 6, dd = elg & 63;
      ushort* grow = Vt + (size_t)(hh * HD + dd) * SEQ + bm * 128;
#pragma unroll
      for (int i = 0; i < 8; ++i) {
        int c = ((tid & 1) * 8 + i + el) & 15;
        *(uint4*)(grow + c * 8) = *(const uint4*)(&vt_tile[el * 128 + c * 8]);
      }
    }
  }
}

// Flash attention R11: R10 structure + overshoot-margin lazy rescale.
// On rescale, m2 = rowmax + 48 (p <= 2^-48, fp32/bf16-safe, o/ell ratio
// exact). Most iterations then take a fast path: cheap per-lane check +
// wave-uniform __all vote, skipping DPP reduce, alpha exp2, ell & o rescale
// (~60 VALU cyc on ~80% of iters — attn is VALU-issue-bound at 55%).
__global__ __launch_bounds__(256, 3) void attn_k(
    const ushort* __restrict__ Qh, const ushort* __restrict__ Ql,
    const ushort* __restrict__ Kh, const ushort* __restrict__ Kl,
    const ushort* __restrict__ Vt, ushort* __restrict__ Ch) {
  __shared__ ushort sKh[2][64 * 64];  // [key][chunk^key&7][8]
  __shared__ ushort sKl[2][64 * 64];
  __shared__ ushort sVt[2][64 * 64];  // [dim][chunk^dim&7][8]
  __shared__ ushort sP[4][16 * 32];   // per-wave 32-key half

  const int tid = threadIdx.x, lane = tid & 63, w = tid >> 6;
  const int col = lane & 15, quad = lane >> 4;
  const int h = blockIdx.y;
  const int q0 = blockIdx.x * 64 + w * 16;

  const ushort* qh_base = Qh + ((size_t)h * SEQ + q0 + col) * HD;
  const ushort* ql_base = Ql + ((size_t)h * SEQ + q0 + col) * HD;
  short8 fqh[2], fql[2];
#pragma unroll
  for (int ks = 0; ks < 2; ++ks) {
    fqh[ks] = *(const short8*)(qh_base + ks * 32 + quad * 8);
    fql[ks] = *(const short8*)(ql_base + ks * 32 + quad * 8);
  }

  const short ONE = (short)0x3F80;
  const short8 ones = {ONE, ONE, ONE, ONE, ONE, ONE, ONE, ONE};

  float m2[4], ell[4];
  f32x4 o[4];
  const f32x4 zz = {0.f, 0.f, 0.f, 0.f};
#pragma unroll
  for (int i = 0; i < 4; ++i) { m2[i] = -1e30f; ell[i] = 0.f; o[i] = zz; }

  const ushort* khg = Kh + (size_t)h * SEQ * HD;  // swizzled [key][64]
  const ushort* klg = Kl + (size_t)h * SEQ * HD;
  const ushort* vtg = Vt + (size_t)h * HD * SEQ;  // swizzled [dim][SEQ]
  ushort* pw = &sP[w][0];

  const ushort* gp[6];
  ushort* lp[6];
  int gstep[6];
#pragma unroll
  for (int i = 0; i < 6; ++i) {
    int idx = w * 6 + i;
    int arr = idx >> 3, j = idx & 7;
    if (arr == 0) {
      gp[i] = khg + (size_t)(j * 8 + (lane >> 3)) * 64 + (lane & 7) * 8;
      lp[i] = &sKh[0][j * 512];
      gstep[i] = 64 * 64;
    } else if (arr == 1) {
      gp[i] = klg + (size_t)(j * 8 + (lane >> 3)) * 64 + (lane & 7) * 8;
      lp[i] = &sKl[0][j * 512];
      gstep[i] = 64 * 64;
    } else {
      gp[i] = vtg + (size_t)(j * 8 + (lane >> 3)) * SEQ + (lane & 7) * 8;
      lp[i] = &sVt[0][j * 512];
      gstep[i] = 64;
    }
  }

#pragma unroll
  for (int i = 0; i < 6; ++i) {
    __builtin_amdgcn_global_load_lds((const GLOBAL_AS unsigned int*)gp[i],
                                     (LDS_AS unsigned int*)lp[i], 16, 0, 0);
    gp[i] += gstep[i];
  }

  const int koff0 = (col * 64 + ((quad ^ (col & 7)) & 7) * 8) * 2;        // ks=0
  const int koff1 = (col * 64 + (((4 + quad) ^ (col & 7)) & 7) * 8) * 2;  // ks=1
  const int fpoff = (col * 32 + ((quad ^ (col & 3) ^ ((col >> 2) & 3)) & 3) * 8) * 2;
  const int voff0 = koff0;
  const int voff1 = koff1;

  auto do_iter = [&](int buf) {
    asm volatile("s_waitcnt vmcnt(0)" ::: "memory");
    __syncthreads();
#pragma unroll
    for (int i = 0; i < 6; ++i) {
      __builtin_amdgcn_global_load_lds(
          (const GLOBAL_AS unsigned int*)gp[i],
          (LDS_AS unsigned int*)(lp[i] + (buf ^ 1) * 4096), 16, 0, 0);
      gp[i] += gstep[i];
    }
    const char* kh = (const char*)&sKh[buf][0];
    const char* kl = (const char*)&sKl[buf][0];
    const char* vt = (const char*)&sVt[buf][0];

    f32x4 s[4];
#pragma unroll
    for (int tn = 0; tn < 4; ++tn) {
      f32x4 a = zz;
      short8 kh0 = *(const short8*)(kh + tn * 2048 + koff0);
      short8 kl0 = *(const short8*)(kl + tn * 2048 + koff0);
      short8 kh1 = *(const short8*)(kh + tn * 2048 + koff1);
      short8 kl1 = *(const short8*)(kl + tn * 2048 + koff1);
      a = __builtin_amdgcn_mfma_f32_16x16x32_bf16(fqh[0], kh0, a, 0, 0, 0);
      a = __builtin_amdgcn_mfma_f32_16x16x32_bf16(fqh[0], kl0, a, 0, 0, 0);
      a = __builtin_amdgcn_mfma_f32_16x16x32_bf16(fql[0], kh0, a, 0, 0, 0);
      a = __builtin_amdgcn_mfma_f32_16x16x32_bf16(fqh[1], kh1, a, 0, 0, 0);
      a = __builtin_amdgcn_mfma_f32_16x16x32_bf16(fqh[1], kl1, a, 0, 0, 0);
      a = __builtin_amdgcn_mfma_f32_16x16x32_bf16(fql[1], kh1, a, 0, 0, 0);
      s[tn] = a;
    }

    // ---- lazy online softmax: fast path when no row exceeds running max ----
    float lm[4];
#pragma unroll
    for (int rr = 0; rr < 4; ++rr)
      lm[rr] = fmaxf(fmaxf(s[0][rr], s[1][rr]), fmaxf(s[2][rr], s[3][rr]));
    int cond = (lm[0] <= m2[0]) && (lm[1] <= m2[1]) &&
               (lm[2] <= m2[2]) && (lm[3] <= m2[3]);
    if (!__all(cond)) {
      float alpha[4];
#pragma unroll
      for (int rr = 0; rr < 4; ++rr) {
        float vm = dpp_max16(lm[rr]);
        float mn = fmaxf(m2[rr], vm + 48.0f);  // overshoot margin
        alpha[rr] = exp2f(m2[rr] - mn);
        m2[rr] = mn;
        ell[rr] *= alpha[rr];
      }
#pragma unroll
      for (int td = 0; td < 4; ++td)
#pragma unroll
        for (int rr = 0; rr < 4; ++rr) o[td][rr] *= alpha[rr];
    }

    f32x4 psum = zz;
#pragma unroll
    for (int hh = 0; hh < 2; ++hh) {
#pragma unroll
      for (int t2 = 0; t2 < 2; ++t2) {
        int tn = hh * 2 + t2;
#pragma unroll
        for (int rr = 0; rr < 4; ++rr) {
          float p = exp2f(s[tn][rr] - m2[rr]);
          int row = quad * 4 + rr;
          int cc = t2 * 16 + col;
          int slot = ((cc >> 3) ^ rr ^ quad) & 3;
          pw[row * 32 + slot * 8 + (cc & 7)] =
              (ushort)(__float_as_uint(p) >> 16);  // trunc: ell uses stored P
        }
      }
      asm volatile("s_waitcnt lgkmcnt(0)" ::: "memory");
      short8 fp = *(const short8*)((const char*)pw + fpoff);
      psum = __builtin_amdgcn_mfma_f32_16x16x32_bf16(fp, ones, psum, 0, 0, 0);
      const int vo = hh ? voff1 : voff0;
#pragma unroll
      for (int td = 0; td < 4; ++td) {
        short8 fv = *(const short8*)(vt + td * 2048 + vo);
        o[td] = __builtin_amdgcn_mfma_f32_16x16x32_bf16(fp, fv, o[td], 0, 0, 0);
      }
    }
#pragma unroll
    for (int rr = 0; rr < 4; ++rr) ell[rr] += psum[rr];
  };

  for (int kb = 0; kb < SEQ; kb += 128) {
    do_iter(0);
    do_iter(1);
  }

#pragma unroll
  for (int td = 0; td < 4; ++td)
#pragma unroll
    for (int rr = 0; rr < 4; ++rr) {
      float v = o[td][rr] / ell[rr];
      int l = q0 + quad * 4 + rr;
      int d = h * 64 + td * 16 + col;
      Ch[(size_t)l * EMB + d] = f2bf(v);
    }
}

extern "C" void kernel_launch(void* const* d_in, const int* in_sizes, int n_in,
                              void* d_out, int out_size, void* d_ws, size_t ws_size,
                              hipStream_t stream) {
  const float* x = (const float*)d_in[0];       // [4096][768]
  const float* qkv_w = (const float*)d_in[1];   // [2304][768]
  const float* out_w = (const float*)d_in[2];   // [768][768]
  const float* out_b = (const float*)d_in[3];   // [768]
  float* out = (float*)d_out;                   // [4096][768]

  char* p = (char*)d_ws;
  auto carve = [&](size_t bytes) {
    char* q = p;
    p += (bytes + 255) & ~(size_t)255;
    return q;
  };
  const size_t NX = (size_t)SEQ * EMB;       // 3,145,728
  const size_t NQW = (size_t)3 * EMB * EMB;  // 1,769,472
  const size_t NOW = (size_t)EMB * EMB;      // 589,824
  const size_t NQKV = (size_t)NH * SEQ * HD; // 3,145,728

  ushort* xh = (ushort*)carve(NX * 2);
  ushort* xl = (ushort*)carve(NX * 2);
  ushort* qwh = (ushort*)carve(NQW * 2);
  ushort* qwl = (ushort*)carve(NQW * 2);
  ushort* owh = (ushort*)carve(NOW * 2);
  ushort* Qh = (ushort*)carve(NQKV * 2);
  ushort* Ql = (ushort*)carve(NQKV * 2);
  ushort* Kh = (ushort*)carve(NQKV * 2);
  ushort* Kl = (ushort*)carve(NQKV * 2);
  ushort* Vt = (ushort*)carve(NQKV * 2);
  ushort* Ch = (ushort*)carve(NX * 2);

  const int ntot4 = (int)((NX + NQW + NOW) / 4);  // 1,376,256 = 5376 * 256
  split_all<<<dim3(ntot4 / 256), 256, 0, stream>>>(
      x, qkv_w, out_w, xh, xl, qwh, qwl, owh, (int)(NX / 4), (int)(NQW / 4));

  // QKV: M=4096, N=2304, K=768 -> scatter epilogue (K/V swizzled; V 1-term)
  gemm_bt_split<<<dim3(32, 18), 256, 0, stream>>>(
      xh, xl, qwh, qwl, SEQ, 3 * EMB, EMB, 1,
      nullptr, nullptr, Qh, Ql, Kh, Kl, Vt);

  attn_k<<<dim3(SEQ / 64, NH), 256, 0, stream>>>(Qh, Ql, Kh, Kl, Vt, Ch);

  // out proj: M=4096, N=768, K=768, 1-term bf16 + bias -> d_out
  gemm_bt_split<<<dim3(32, 6), 256, 0, stream>>>(
      Ch, Ch, owh, owh, SEQ, EMB, EMB, 2,
      out, out_b, nullptr, nullptr, nullptr, nullptr, nullptr);
}